// Round 1
// baseline (119808.435 us; speedup 1.0000x reference)
//
#include <hip/hip_runtime.h>
#include <hip/hip_cooperative_groups.h>

namespace cg = cooperative_groups;

typedef float f32x4 __attribute__((ext_vector_type(4)));
typedef short bf16x8 __attribute__((ext_vector_type(8)));
typedef _Float16 f16x2 __attribute__((ext_vector_type(2)));
typedef _Float16 f16x4 __attribute__((ext_vector_type(4)));
typedef _Float16 f16x8 __attribute__((ext_vector_type(8)));

#define SEQ 2048
#define HD 2048
#define NG 8192
#define KD 2048
#define NB 256
#define NT 512
#define PAD_CH 136   // fp16 elems per h-chunk incl pad (128 data + 8 pad); 272B stride -> 2-way max bank conflict

__device__ __forceinline__ unsigned short f32_to_bf16_rne(float f) {
    unsigned int u = __float_as_uint(f);
    u += 0x7FFFu + ((u >> 16) & 1u);
    return (unsigned short)(u >> 16);
}

__global__ void cvt_f16_kernel(const float* __restrict__ in, _Float16* __restrict__ out, int n) {
    for (int i = blockIdx.x * blockDim.x + threadIdx.x; i < n; i += gridDim.x * blockDim.x)
        out[i] = (_Float16)in[i];
}

// ---------------- GEMM: xg[s][g] = sum_k x[s][k] * w_ih[g][k] + b_ih[g] + b_hh[g] ----------------
// 128x128 tile, BK=32, 4 waves each computing 64x64 via 4x4 frags of mfma_f32_16x16x32_bf16.
// A- and B-fragments use IDENTICAL lane patterns -> result independent of the unknown lane->k permutation.
__global__ __launch_bounds__(256) void gemm_xg(
    const float* __restrict__ A,    // x   [2048][2048]
    const float* __restrict__ B,    // w_ih[8192][2048]
    const float* __restrict__ bih, const float* __restrict__ bhh,
    float* __restrict__ C)          // xg  [2048][8192]
{
    __shared__ unsigned short As[128 * 32];
    __shared__ unsigned short Bs[128 * 32];
    const int tid = threadIdx.x;
    const int bm = blockIdx.x, bn = blockIdx.y;
    const int wave = tid >> 6, lane = tid & 63;
    const int wr = wave >> 1, wc = wave & 1;
    const int l15 = lane & 15, l4 = lane >> 4;

    f32x4 acc[4][4];
    #pragma unroll
    for (int i = 0; i < 4; ++i)
        #pragma unroll
        for (int j = 0; j < 4; ++j) {
            f32x4 z = {0.f, 0.f, 0.f, 0.f};
            acc[i][j] = z;
        }

    for (int k0 = 0; k0 < KD; k0 += 32) {
        #pragma unroll
        for (int i = 0; i < 2; ++i) {
            int idx = tid + i * 256;           // 0..511
            int row = idx >> 2, c8 = idx & 3;  // 128 rows x 4 chunks of 8
            const float* ga = A + (size_t)(bm * 128 + row) * KD + k0 + c8 * 8;
            float4 a0 = *(const float4*)ga;
            float4 a1 = *(const float4*)(ga + 4);
            bf16x8 av;
            av[0] = (short)f32_to_bf16_rne(a0.x); av[1] = (short)f32_to_bf16_rne(a0.y);
            av[2] = (short)f32_to_bf16_rne(a0.z); av[3] = (short)f32_to_bf16_rne(a0.w);
            av[4] = (short)f32_to_bf16_rne(a1.x); av[5] = (short)f32_to_bf16_rne(a1.y);
            av[6] = (short)f32_to_bf16_rne(a1.z); av[7] = (short)f32_to_bf16_rne(a1.w);
            *(bf16x8*)&As[row * 32 + c8 * 8] = av;
            const float* gb = B + (size_t)(bn * 128 + row) * KD + k0 + c8 * 8;
            float4 b0 = *(const float4*)gb;
            float4 b1 = *(const float4*)(gb + 4);
            bf16x8 bv;
            bv[0] = (short)f32_to_bf16_rne(b0.x); bv[1] = (short)f32_to_bf16_rne(b0.y);
            bv[2] = (short)f32_to_bf16_rne(b0.z); bv[3] = (short)f32_to_bf16_rne(b0.w);
            bv[4] = (short)f32_to_bf16_rne(b1.x); bv[5] = (short)f32_to_bf16_rne(b1.y);
            bv[6] = (short)f32_to_bf16_rne(b1.z); bv[7] = (short)f32_to_bf16_rne(b1.w);
            *(bf16x8*)&Bs[row * 32 + c8 * 8] = bv;
        }
        __syncthreads();
        bf16x8 af[4], bfr[4];
        #pragma unroll
        for (int m = 0; m < 4; ++m) af[m] = *(const bf16x8*)&As[(wr * 64 + m * 16 + l15) * 32 + l4 * 8];
        #pragma unroll
        for (int n = 0; n < 4; ++n) bfr[n] = *(const bf16x8*)&Bs[(wc * 64 + n * 16 + l15) * 32 + l4 * 8];
        #pragma unroll
        for (int m = 0; m < 4; ++m)
            #pragma unroll
            for (int n = 0; n < 4; ++n)
                acc[m][n] = __builtin_amdgcn_mfma_f32_16x16x32_bf16(af[m], bfr[n], acc[m][n], 0, 0, 0);
        __syncthreads();
    }
    // epilogue: C row = 4*(lane>>4)+reg, col = lane&15 (m89-verified C/D layout)
    #pragma unroll
    for (int m = 0; m < 4; ++m) {
        #pragma unroll
        for (int n = 0; n < 4; ++n) {
            int col = bn * 128 + wc * 64 + n * 16 + l15;
            float bias = bih[col] + bhh[col];
            int row0 = bm * 128 + wr * 64 + m * 16 + l4 * 4;
            #pragma unroll
            for (int r = 0; r < 4; ++r)
                C[(size_t)(row0 + r) * NG + col] = acc[m][n][r] + bias;
        }
    }
}

// ---------------- Persistent cooperative recurrence kernel ----------------
// 256 blocks x 512 threads. Per step:
//  phase1: (redundant per block) h_{t-1} = o * tanh(LN(c_raw)) -> LDS (fp16, padded);
//          slice-owner threads write y[t-1] / c_ln slice; then GEMV rows [32b,32b+32):
//          gates = xg[t] + W h, + per-gate partial stats.   grid.sync
//  phase2: slice [8b,8b+8): 4 gate LNs + activations; c_raw update; o; cy partial stats. grid.sync
__global__ __launch_bounds__(512) void lstm_rec(
    const float* __restrict__ xg,          // [SEQ][NG]
    const _Float16* __restrict__ Whh,      // [NG][HD] fp16
    const float* __restrict__ gamma,       // [5][HD]
    const float* __restrict__ beta,        // [5][HD]
    float* __restrict__ gates,             // [NG]
    float* __restrict__ rawc,              // [HD]
    float* __restrict__ obuf,              // [HD]
    float* __restrict__ p1s, float* __restrict__ p1q,   // [NB] gate partial stats
    float* __restrict__ p2s, float* __restrict__ p2q,   // [NB] cy partial stats
    float* __restrict__ yout)              // y[SEQ][HD], hy[HD], cy[HD]
{
    cg::grid_group grid = cg::this_grid();
    const int b = blockIdx.x;
    const int t = threadIdx.x;
    const int wave = t >> 6;
    const int lane = t & 63;

    __shared__ _Float16 hlds[16 * PAD_CH];  // h, 16 chunks of 128 (+8 pad)
    __shared__ float lnc_s[8];              // this block's c_ln slice
    __shared__ float red[64];
    __shared__ float stats[8];

    float* hyout = yout + (size_t)SEQ * HD;
    float* cyout = hyout + HD;
    const float* gam4 = gamma + 4 * HD;
    const float* bet4 = beta + 4 * HD;
    const float invH = 1.0f / 2048.0f;

    for (int step = 0; step <= SEQ; ++step) {
        // ---------- phase 1a: h_{step-1} (redundant per block) ----------
        if (step == 0) {
            for (int k = t; k < 16 * PAD_CH; k += NT) hlds[k] = (_Float16)0.0f;
            if (t < 8) lnc_s[t] = 0.0f;
        } else {
            float s = (t < NB) ? p2s[t] : 0.0f;
            float q = (t < NB) ? p2q[t] : 0.0f;
            #pragma unroll
            for (int off = 32; off; off >>= 1) { s += __shfl_down(s, off); q += __shfl_down(q, off); }
            if (lane == 0) { red[wave] = s; red[8 + wave] = q; }
            __syncthreads();
            if (t == 0) {
                float ss = 0.f, qq = 0.f;
                #pragma unroll
                for (int w = 0; w < 8; ++w) { ss += red[w]; qq += red[8 + w]; }
                float m = ss * invH;
                float v = qq * invH - m * m;
                stats[0] = m; stats[1] = rsqrtf(v + 1e-5f);
            }
            __syncthreads();
            const float m = stats[0], rs = stats[1];
            const int kbase = t * 4;
            float4 rc4 = *(const float4*)&rawc[kbase];
            float4 oo4 = *(const float4*)&obuf[kbase];
            const float* rcp = &rc4.x;
            const float* oop = &oo4.x;
            float lc[4], hv[4];
            #pragma unroll
            for (int j = 0; j < 4; ++j) {
                float lnc = (rcp[j] - m) * rs * gam4[kbase + j] + bet4[kbase + j];
                lc[j] = lnc;
                float ax = fabsf(lnc);
                float e = __expf(-2.0f * ax);
                float th = __builtin_copysignf((1.0f - e) / (1.0f + e), lnc);
                hv[j] = oop[j] * th;
            }
            f16x4 hh;
            hh[0] = (_Float16)hv[0]; hh[1] = (_Float16)hv[1];
            hh[2] = (_Float16)hv[2]; hh[3] = (_Float16)hv[3];
            *(f16x4*)&hlds[(kbase >> 7) * PAD_CH + (kbase & 127)] = hh;
            if ((t >> 1) == b) {  // threads 2b, 2b+1 own global slice [8b,8b+8)
                float4 ho = {hv[0], hv[1], hv[2], hv[3]};
                *(float4*)&yout[(size_t)(step - 1) * HD + kbase] = ho;
                lnc_s[(t & 1) * 4 + 0] = lc[0]; lnc_s[(t & 1) * 4 + 1] = lc[1];
                lnc_s[(t & 1) * 4 + 2] = lc[2]; lnc_s[(t & 1) * 4 + 3] = lc[3];
                if (step == SEQ) {
                    *(float4*)&hyout[kbase] = ho;
                    float4 co = {lc[0], lc[1], lc[2], lc[3]};
                    *(float4*)&cyout[kbase] = co;
                }
            }
        }
        __syncthreads();
        if (step == SEQ) break;

        // ---------- phase 1b: GEMV rows [32b, 32b+32) ----------
        {
            const int row = t >> 4;   // 0..31
            const int sub = t & 15;   // 0..15, k-chunk of 128
            const _Float16* wrow = Whh + (size_t)(b * 32 + row) * HD + sub * 128;
            const _Float16* hch = &hlds[sub * PAD_CH];
            float acc = 0.0f;
            #pragma unroll
            for (int i = 0; i < 16; ++i) {
                f16x8 wv = *(const f16x8*)(wrow + i * 8);
                f16x8 hv = *(const f16x8*)(hch + i * 8);
                const f16x2* w2 = (const f16x2*)&wv;
                const f16x2* h2 = (const f16x2*)&hv;
                acc = __builtin_amdgcn_fdot2(w2[0], h2[0], acc, false);
                acc = __builtin_amdgcn_fdot2(w2[1], h2[1], acc, false);
                acc = __builtin_amdgcn_fdot2(w2[2], h2[2], acc, false);
                acc = __builtin_amdgcn_fdot2(w2[3], h2[3], acc, false);
            }
            #pragma unroll
            for (int off = 1; off < 16; off <<= 1) acc += __shfl_xor(acc, off);
            if (sub == 0) {
                float gv = xg[(size_t)step * NG + b * 32 + row] + acc;
                gates[b * 32 + row] = gv;
                red[32 + row] = gv;
            }
        }
        __syncthreads();
        if (t == 0) {
            float ss = 0.f, qq = 0.f;
            #pragma unroll
            for (int r = 0; r < 32; ++r) { float v = red[32 + r]; ss += v; qq += v * v; }
            p1s[b] = ss; p1q[b] = qq;
        }
        grid.sync();

        // ---------- phase 2: elementwise slice [8b, 8b+8) ----------
        if (wave < 4) {  // wave w reduces gate w's 64 block-partials
            float s = p1s[wave * 64 + lane];
            float q = p1q[wave * 64 + lane];
            #pragma unroll
            for (int off = 32; off; off >>= 1) { s += __shfl_down(s, off); q += __shfl_down(q, off); }
            if (lane == 0) {
                float m = s * invH;
                float v = q * invH - m * m;
                stats[2 * wave] = m; stats[2 * wave + 1] = rsqrtf(v + 1e-5f);
            }
        }
        __syncthreads();
        if (t < 8) {
            const int k = b * 8 + t;
            float lv[4];
            #pragma unroll
            for (int g = 0; g < 4; ++g) {
                float raw = gates[g * HD + k];
                lv[g] = (raw - stats[2 * g]) * stats[2 * g + 1] * gamma[g * HD + k] + beta[g * HD + k];
            }
            float ig = 1.0f / (1.0f + __expf(-lv[0]));
            float fg = 1.0f / (1.0f + __expf(-lv[1]));
            float axg = fabsf(lv[2]);
            float eg = __expf(-2.0f * axg);
            float gg = __builtin_copysignf((1.0f - eg) / (1.0f + eg), lv[2]);
            float og = 1.0f / (1.0f + __expf(-lv[3]));
            float rcv = fg * lnc_s[t] + ig * gg;
            rawc[k] = rcv;
            obuf[k] = og;
            red[t] = rcv;
        }
        __syncthreads();
        if (t == 0) {
            float ss = 0.f, qq = 0.f;
            #pragma unroll
            for (int r = 0; r < 8; ++r) { float v = red[r]; ss += v; qq += v * v; }
            p2s[b] = ss; p2q[b] = qq;
        }
        grid.sync();
    }
}

extern "C" void kernel_launch(void* const* d_in, const int* in_sizes, int n_in,
                              void* d_out, int out_size, void* d_ws, size_t ws_size,
                              hipStream_t stream) {
    const float* x   = (const float*)d_in[0];
    const float* wih = (const float*)d_in[1];
    const float* whh = (const float*)d_in[2];
    const float* bih = (const float*)d_in[3];
    const float* bhh = (const float*)d_in[4];
    const float* gam = (const float*)d_in[5];
    const float* bet = (const float*)d_in[6];
    float* out = (float*)d_out;

    char* ws = (char*)d_ws;
    size_t off = 0;
    auto carve = [&](size_t bytes) -> void* {
        void* p = ws + off;
        off += (bytes + 255) & ~(size_t)255;
        return p;
    };
    float* xg      = (float*)carve(sizeof(float) * (size_t)SEQ * NG);      // 64 MB
    _Float16* whhf = (_Float16*)carve(sizeof(_Float16) * (size_t)NG * HD); // 32 MB
    float* gates   = (float*)carve(sizeof(float) * NG);
    float* rawc    = (float*)carve(sizeof(float) * HD);
    float* obuf    = (float*)carve(sizeof(float) * HD);
    float* p1s     = (float*)carve(sizeof(float) * NB);
    float* p1q     = (float*)carve(sizeof(float) * NB);
    float* p2s     = (float*)carve(sizeof(float) * NB);
    float* p2q     = (float*)carve(sizeof(float) * NB);

    cvt_f16_kernel<<<2048, 256, 0, stream>>>(whh, whhf, NG * HD);
    dim3 ggrid(16, 64);
    gemm_xg<<<ggrid, 256, 0, stream>>>(x, wih, bih, bhh, xg);

    void* args[] = { (void*)&xg, (void*)&whhf, (void*)&gam, (void*)&bet,
                     (void*)&gates, (void*)&rawc, (void*)&obuf,
                     (void*)&p1s, (void*)&p1q, (void*)&p2s, (void*)&p2q, (void*)&out };
    hipLaunchCooperativeKernel((void*)lstm_rec, dim3(NB), dim3(NT), args, 0, stream);
}

// Round 2
// 35689.227 us; speedup vs baseline: 3.3570x; 3.3570x over previous
//
#include <hip/hip_runtime.h>

typedef float f32x4 __attribute__((ext_vector_type(4)));
typedef short bf16x8 __attribute__((ext_vector_type(8)));
typedef _Float16 f16x2 __attribute__((ext_vector_type(2)));
typedef _Float16 f16x4 __attribute__((ext_vector_type(4)));
typedef _Float16 f16x8 __attribute__((ext_vector_type(8)));

#define SEQ 2048
#define HD 2048
#define NG 8192
#define KD 2048
#define NB 256
#define NT 512
#define PAD_CH 136                    // fp16 per 128-elem chunk incl. 8 pad
#define WROW_STRIDE (16 * PAD_CH)     // 2176 fp16 per W row in LDS

__device__ __forceinline__ unsigned short f32_to_bf16_rne(float f) {
    unsigned int u = __float_as_uint(f);
    u += 0x7FFFu + ((u >> 16) & 1u);
    return (unsigned short)(u >> 16);
}

__global__ void cvt_f16_kernel(const float* __restrict__ in, _Float16* __restrict__ out, int n) {
    for (int i = blockIdx.x * blockDim.x + threadIdx.x; i < n; i += gridDim.x * blockDim.x)
        out[i] = (_Float16)in[i];
}

// ---------------- GEMM: xg[s][g] = sum_k x[s][k] * w_ih[g][k] + b_ih[g] + b_hh[g] ----------------
__global__ __launch_bounds__(256) void gemm_xg(
    const float* __restrict__ A,    // x   [2048][2048]
    const float* __restrict__ B,    // w_ih[8192][2048]
    const float* __restrict__ bih, const float* __restrict__ bhh,
    float* __restrict__ C)          // xg  [2048][8192]
{
    __shared__ unsigned short As[128 * 32];
    __shared__ unsigned short Bs[128 * 32];
    const int tid = threadIdx.x;
    const int bm = blockIdx.x, bn = blockIdx.y;
    const int wave = tid >> 6, lane = tid & 63;
    const int wr = wave >> 1, wc = wave & 1;
    const int l15 = lane & 15, l4 = lane >> 4;

    f32x4 acc[4][4];
    #pragma unroll
    for (int i = 0; i < 4; ++i)
        #pragma unroll
        for (int j = 0; j < 4; ++j) {
            f32x4 z = {0.f, 0.f, 0.f, 0.f};
            acc[i][j] = z;
        }

    for (int k0 = 0; k0 < KD; k0 += 32) {
        #pragma unroll
        for (int i = 0; i < 2; ++i) {
            int idx = tid + i * 256;
            int row = idx >> 2, c8 = idx & 3;
            const float* ga = A + (size_t)(bm * 128 + row) * KD + k0 + c8 * 8;
            float4 a0 = *(const float4*)ga;
            float4 a1 = *(const float4*)(ga + 4);
            bf16x8 av;
            av[0] = (short)f32_to_bf16_rne(a0.x); av[1] = (short)f32_to_bf16_rne(a0.y);
            av[2] = (short)f32_to_bf16_rne(a0.z); av[3] = (short)f32_to_bf16_rne(a0.w);
            av[4] = (short)f32_to_bf16_rne(a1.x); av[5] = (short)f32_to_bf16_rne(a1.y);
            av[6] = (short)f32_to_bf16_rne(a1.z); av[7] = (short)f32_to_bf16_rne(a1.w);
            *(bf16x8*)&As[row * 32 + c8 * 8] = av;
            const float* gb = B + (size_t)(bn * 128 + row) * KD + k0 + c8 * 8;
            float4 b0 = *(const float4*)gb;
            float4 b1 = *(const float4*)(gb + 4);
            bf16x8 bv;
            bv[0] = (short)f32_to_bf16_rne(b0.x); bv[1] = (short)f32_to_bf16_rne(b0.y);
            bv[2] = (short)f32_to_bf16_rne(b0.z); bv[3] = (short)f32_to_bf16_rne(b0.w);
            bv[4] = (short)f32_to_bf16_rne(b1.x); bv[5] = (short)f32_to_bf16_rne(b1.y);
            bv[6] = (short)f32_to_bf16_rne(b1.z); bv[7] = (short)f32_to_bf16_rne(b1.w);
            *(bf16x8*)&Bs[row * 32 + c8 * 8] = bv;
        }
        __syncthreads();
        bf16x8 af[4], bfr[4];
        #pragma unroll
        for (int m = 0; m < 4; ++m) af[m] = *(const bf16x8*)&As[(wr * 64 + m * 16 + l15) * 32 + l4 * 8];
        #pragma unroll
        for (int n = 0; n < 4; ++n) bfr[n] = *(const bf16x8*)&Bs[(wc * 64 + n * 16 + l15) * 32 + l4 * 8];
        #pragma unroll
        for (int m = 0; m < 4; ++m)
            #pragma unroll
            for (int n = 0; n < 4; ++n)
                acc[m][n] = __builtin_amdgcn_mfma_f32_16x16x32_bf16(af[m], bfr[n], acc[m][n], 0, 0, 0);
        __syncthreads();
    }
    #pragma unroll
    for (int m = 0; m < 4; ++m) {
        #pragma unroll
        for (int n = 0; n < 4; ++n) {
            int col = bn * 128 + wc * 64 + n * 16 + l15;
            float bias = bih[col] + bhh[col];
            int row0 = bm * 128 + wr * 64 + m * 16 + l4 * 4;
            #pragma unroll
            for (int r = 0; r < 4; ++r)
                C[(size_t)(row0 + r) * NG + col] = acc[m][n][r] + bias;
        }
    }
}

// ---------------- custom flag-array grid barrier ----------------
// block b release-stores gen to flags[b]; wave0 polls all 256 flags (4/lane).
// No atomic RMW contention; monotone gen (no reset races); flags memset per launch.
__device__ __forceinline__ void grid_barrier(unsigned* flags, unsigned gen) {
    __syncthreads();
    const int t = threadIdx.x;
    if (t == 0) {
        __threadfence();   // release: gate stores (all waves, ordered by syncthreads) -> coherence point
        __hip_atomic_store(&flags[blockIdx.x], gen, __ATOMIC_RELAXED, __HIP_MEMORY_SCOPE_AGENT);
    }
    if (t < 64) {
        const unsigned* f4 = flags + t * 4;
        for (;;) {
            unsigned a = __hip_atomic_load(&f4[0], __ATOMIC_RELAXED, __HIP_MEMORY_SCOPE_AGENT);
            unsigned b = __hip_atomic_load(&f4[1], __ATOMIC_RELAXED, __HIP_MEMORY_SCOPE_AGENT);
            unsigned c = __hip_atomic_load(&f4[2], __ATOMIC_RELAXED, __HIP_MEMORY_SCOPE_AGENT);
            unsigned d = __hip_atomic_load(&f4[3], __ATOMIC_RELAXED, __HIP_MEMORY_SCOPE_AGENT);
            bool ok = (a >= gen) && (b >= gen) && (c >= gen) && (d >= gen);
            if (__all(ok)) break;
            __builtin_amdgcn_s_sleep(1);
        }
        if (t == 0) __threadfence();  // acquire: invalidate L1/L2 before gate reads
    }
    __syncthreads();
}

// ---------------- Persistent recurrence: 1 grid barrier per step ----------------
// Per step: GEMV(h in LDS, W in LDS) -> write own 32 gates -> barrier ->
// every block redundantly: read all 8192 gates, 4 gate LN stats, activations,
// c-update (c,o in registers), cy LN stats, h -> LDS. Block b writes y slice [8b,8b+8).
__global__ __launch_bounds__(512) void lstm_rec(
    const float* __restrict__ xg,          // [SEQ][NG]
    const _Float16* __restrict__ Whh,      // [NG][HD] fp16
    const float* __restrict__ gamma,       // [5][HD]
    const float* __restrict__ beta,        // [5][HD]
    float* __restrict__ gates,             // [2][NG] double-buffered
    unsigned* __restrict__ flags,          // [NB]
    float* __restrict__ yout)              // y[SEQ][HD], hy[HD], cy[HD]
{
    extern __shared__ char smem[];
    _Float16* wlds = (_Float16*)smem;                                  // 32 rows * 2176
    _Float16* hlds = (_Float16*)(smem + (size_t)32 * WROW_STRIDE * 2); // 16 * 136
    float* red   = (float*)((char*)hlds + 16 * PAD_CH * 2);            // 64
    float* red2  = red + 64;                                           // 8
    float* stats = red2 + 8;                                           // 12

    const int b = blockIdx.x;
    const int t = threadIdx.x;
    const int wave = t >> 6, lane = t & 63;
    const int p = t * 4;                   // this thread's 4 H-positions

    // ---- stage W_hh rows [32b, 32b+32) into LDS (chunk-padded) ----
    for (int idx = t; idx < 32 * 256; idx += NT) {        // 16B granules
        int r = idx >> 8, g = idx & 255;
        f16x8 v = *(const f16x8*)(Whh + (size_t)(b * 32 + r) * HD + g * 8);
        *(f16x8*)&wlds[r * WROW_STRIDE + (g >> 4) * PAD_CH + (g & 15) * 8] = v;
    }
    for (int k = t; k < 16 * PAD_CH; k += NT) hlds[k] = (_Float16)0.0f;

    // per-thread LN params (constant across steps)
    float4 gm[4], bt[4];
    #pragma unroll
    for (int g = 0; g < 4; ++g) {
        gm[g] = *(const float4*)&gamma[g * HD + p];
        bt[g] = *(const float4*)&beta[g * HD + p];
    }
    float4 gm4 = *(const float4*)&gamma[4 * HD + p];
    float4 bt4 = *(const float4*)&beta[4 * HD + p];

    float* hyout = yout + (size_t)SEQ * HD;
    float* cyout = hyout + HD;
    const float invH = 1.0f / 2048.0f;

    float cprev[4] = {0.f, 0.f, 0.f, 0.f};
    __syncthreads();

    const int row = t >> 4, sub = t & 15;
    const _Float16* wr = wlds + row * WROW_STRIDE + sub * PAD_CH;
    const _Float16* hch = hlds + sub * PAD_CH;
    const int grow = b * 32 + row;

    for (int step = 0; step < SEQ; ++step) {
        float* gb = gates + (size_t)(step & 1) * NG;

        // ---------- GEMV: gates[grow] = xg[step][grow] + W[grow] . h ----------
        float xgv = xg[(size_t)step * NG + grow];
        float acc = 0.0f;
        #pragma unroll
        for (int i = 0; i < 16; ++i) {
            f16x8 wv = *(const f16x8*)(wr + i * 8);
            f16x8 hv = *(const f16x8*)(hch + i * 8);
            const f16x2* w2 = (const f16x2*)&wv;
            const f16x2* h2 = (const f16x2*)&hv;
            acc = __builtin_amdgcn_fdot2(w2[0], h2[0], acc, false);
            acc = __builtin_amdgcn_fdot2(w2[1], h2[1], acc, false);
            acc = __builtin_amdgcn_fdot2(w2[2], h2[2], acc, false);
            acc = __builtin_amdgcn_fdot2(w2[3], h2[3], acc, false);
        }
        #pragma unroll
        for (int off = 1; off < 16; off <<= 1) acc += __shfl_xor(acc, off);
        if (sub == 0) gb[grow] = xgv + acc;

        // ---------- single grid barrier ----------
        grid_barrier(flags, (unsigned)(step + 1));

        // ---------- redundant post-phase (identical in every block) ----------
        // read 4 gate values at this thread's positions
        float4 gv[4];
        #pragma unroll
        for (int g = 0; g < 4; ++g) gv[g] = *(const float4*)&gb[g * HD + p];

        // per-gate stats: each thread contributes (s,q) for all 4 gates
        #pragma unroll
        for (int g = 0; g < 4; ++g) {
            const float* vp = (const float*)&gv[g];
            float s = vp[0] + vp[1] + vp[2] + vp[3];
            float q = vp[0]*vp[0] + vp[1]*vp[1] + vp[2]*vp[2] + vp[3]*vp[3];
            #pragma unroll
            for (int off = 1; off < 64; off <<= 1) { s += __shfl_xor(s, off); q += __shfl_xor(q, off); }
            if (lane == 0) { red[wave * 8 + g * 2] = s; red[wave * 8 + g * 2 + 1] = q; }
        }
        __syncthreads();
        if (t < 4) {
            float ss = 0.f, qq = 0.f;
            #pragma unroll
            for (int w = 0; w < 8; ++w) { ss += red[w * 8 + t * 2]; qq += red[w * 8 + t * 2 + 1]; }
            float m = ss * invH;
            float v = qq * invH - m * m;
            stats[2 * t] = m; stats[2 * t + 1] = rsqrtf(v + 1e-5f);
        }
        __syncthreads();

        const float m0 = stats[0], r0 = stats[1], m1 = stats[2], r1 = stats[3];
        const float m2 = stats[4], r2 = stats[5], m3 = stats[6], r3 = stats[7];

        float rcv[4], og4[4];
        float s2 = 0.f, q2 = 0.f;
        #pragma unroll
        for (int j = 0; j < 4; ++j) {
            float li = (((const float*)&gv[0])[j] - m0) * r0 * ((const float*)&gm[0])[j] + ((const float*)&bt[0])[j];
            float lf = (((const float*)&gv[1])[j] - m1) * r1 * ((const float*)&gm[1])[j] + ((const float*)&bt[1])[j];
            float lg = (((const float*)&gv[2])[j] - m2) * r2 * ((const float*)&gm[2])[j] + ((const float*)&bt[2])[j];
            float lo = (((const float*)&gv[3])[j] - m3) * r3 * ((const float*)&gm[3])[j] + ((const float*)&bt[3])[j];
            float ig = 1.0f / (1.0f + __expf(-li));
            float fg = 1.0f / (1.0f + __expf(-lf));
            float axg = fabsf(lg);
            float eg = __expf(-2.0f * axg);
            float gg = __builtin_copysignf((1.0f - eg) / (1.0f + eg), lg);
            float og = 1.0f / (1.0f + __expf(-lo));
            float rv = fg * cprev[j] + ig * gg;
            rcv[j] = rv; og4[j] = og;
            s2 += rv; q2 += rv * rv;
        }
        #pragma unroll
        for (int off = 1; off < 64; off <<= 1) { s2 += __shfl_xor(s2, off); q2 += __shfl_xor(q2, off); }
        if (lane == 0) { red[wave * 2] = s2; red[wave * 2 + 1] = q2; }
        __syncthreads();
        if (t == 0) {
            float ss = 0.f, qq = 0.f;
            #pragma unroll
            for (int w = 0; w < 8; ++w) { ss += red[w * 2]; qq += red[w * 2 + 1]; }
            float m = ss * invH;
            float v = qq * invH - m * m;
            stats[8] = m; stats[9] = rsqrtf(v + 1e-5f);
        }
        __syncthreads();
        const float mc = stats[8], rc = stats[9];

        float hvf[4], lcf[4];
        f16x4 hh;
        #pragma unroll
        for (int j = 0; j < 4; ++j) {
            float lc = (rcv[j] - mc) * rc * ((const float*)&gm4)[j] + ((const float*)&bt4)[j];
            cprev[j] = lc;
            float ax = fabsf(lc);
            float e = __expf(-2.0f * ax);
            float th = __builtin_copysignf((1.0f - e) / (1.0f + e), lc);
            float hv = og4[j] * th;
            hvf[j] = hv; lcf[j] = lc;
            hh[j] = (_Float16)hv;
        }
        *(f16x4*)&hlds[(p >> 7) * PAD_CH + (p & 127)] = hh;

        if ((t >> 1) == b) {   // this block owns global slice [8b, 8b+8)
            float4 ho = {hvf[0], hvf[1], hvf[2], hvf[3]};
            *(float4*)&yout[(size_t)step * HD + p] = ho;
            if (step == SEQ - 1) {
                *(float4*)&hyout[p] = ho;
                float4 co = {lcf[0], lcf[1], lcf[2], lcf[3]};
                *(float4*)&cyout[p] = co;
            }
        }
        __syncthreads();   // hlds ready for next GEMV
    }
}

extern "C" void kernel_launch(void* const* d_in, const int* in_sizes, int n_in,
                              void* d_out, int out_size, void* d_ws, size_t ws_size,
                              hipStream_t stream) {
    const float* x   = (const float*)d_in[0];
    const float* wih = (const float*)d_in[1];
    const float* whh = (const float*)d_in[2];
    const float* bih = (const float*)d_in[3];
    const float* bhh = (const float*)d_in[4];
    const float* gam = (const float*)d_in[5];
    const float* bet = (const float*)d_in[6];
    float* out = (float*)d_out;

    char* ws = (char*)d_ws;
    size_t off = 0;
    auto carve = [&](size_t bytes) -> void* {
        void* pp = ws + off;
        off += (bytes + 255) & ~(size_t)255;
        return pp;
    };
    float* xg      = (float*)carve(sizeof(float) * (size_t)SEQ * NG);      // 64 MB
    _Float16* whhf = (_Float16*)carve(sizeof(_Float16) * (size_t)NG * HD); // 32 MB
    float* gates   = (float*)carve(sizeof(float) * 2 * NG);
    unsigned* flags = (unsigned*)carve(sizeof(unsigned) * NB);

    cvt_f16_kernel<<<2048, 256, 0, stream>>>(whh, whhf, NG * HD);
    dim3 ggrid(16, 64);
    gemm_xg<<<ggrid, 256, 0, stream>>>(x, wih, bih, bhh, xg);
    hipMemsetAsync(flags, 0, sizeof(unsigned) * NB, stream);

    size_t ldsbytes = (size_t)32 * WROW_STRIDE * 2 + (size_t)16 * PAD_CH * 2 + (64 + 8 + 12) * 4;
    hipFuncSetAttribute((const void*)lstm_rec, hipFuncAttributeMaxDynamicSharedMemorySize, (int)ldsbytes);

    void* args[] = { (void*)&xg, (void*)&whhf, (void*)&gam, (void*)&bet,
                     (void*)&gates, (void*)&flags, (void*)&out };
    hipLaunchCooperativeKernel((void*)lstm_rec, dim3(NB), dim3(NT), args, (unsigned)ldsbytes, stream);
}

// Round 3
// 19280.058 us; speedup vs baseline: 6.2141x; 1.8511x over previous
//
#include <hip/hip_runtime.h>

typedef float f32x4 __attribute__((ext_vector_type(4)));
typedef short bf16x8 __attribute__((ext_vector_type(8)));
typedef _Float16 f16x2 __attribute__((ext_vector_type(2)));
typedef _Float16 f16x4 __attribute__((ext_vector_type(4)));
typedef _Float16 f16x8 __attribute__((ext_vector_type(8)));

#define SEQ 2048
#define HD 2048
#define NG 8192
#define KD 2048
#define NB 256
#define NT 512
#define PAD_CH 136                    // fp16 per 128-elem chunk incl. 8 pad
#define WROW_STRIDE (16 * PAD_CH)     // 2176 fp16 per W row in LDS

__device__ __forceinline__ unsigned short f32_to_bf16_rne(float f) {
    unsigned int u = __float_as_uint(f);
    u += 0x7FFFu + ((u >> 16) & 1u);
    return (unsigned short)(u >> 16);
}

__global__ void cvt_f16_kernel(const float* __restrict__ in, _Float16* __restrict__ out, int n) {
    for (int i = blockIdx.x * blockDim.x + threadIdx.x; i < n; i += gridDim.x * blockDim.x)
        out[i] = (_Float16)in[i];
}

// ---------------- GEMM: xg[s][g] = sum_k x[s][k] * w_ih[g][k] + b_ih[g] + b_hh[g] ----------------
__global__ __launch_bounds__(256) void gemm_xg(
    const float* __restrict__ A,    // x   [2048][2048]
    const float* __restrict__ B,    // w_ih[8192][2048]
    const float* __restrict__ bih, const float* __restrict__ bhh,
    float* __restrict__ C)          // xg  [2048][8192]
{
    __shared__ unsigned short As[128 * 32];
    __shared__ unsigned short Bs[128 * 32];
    const int tid = threadIdx.x;
    const int bm = blockIdx.x, bn = blockIdx.y;
    const int wave = tid >> 6, lane = tid & 63;
    const int wr = wave >> 1, wc = wave & 1;
    const int l15 = lane & 15, l4 = lane >> 4;

    f32x4 acc[4][4];
    #pragma unroll
    for (int i = 0; i < 4; ++i)
        #pragma unroll
        for (int j = 0; j < 4; ++j) {
            f32x4 z = {0.f, 0.f, 0.f, 0.f};
            acc[i][j] = z;
        }

    for (int k0 = 0; k0 < KD; k0 += 32) {
        #pragma unroll
        for (int i = 0; i < 2; ++i) {
            int idx = tid + i * 256;
            int row = idx >> 2, c8 = idx & 3;
            const float* ga = A + (size_t)(bm * 128 + row) * KD + k0 + c8 * 8;
            float4 a0 = *(const float4*)ga;
            float4 a1 = *(const float4*)(ga + 4);
            bf16x8 av;
            av[0] = (short)f32_to_bf16_rne(a0.x); av[1] = (short)f32_to_bf16_rne(a0.y);
            av[2] = (short)f32_to_bf16_rne(a0.z); av[3] = (short)f32_to_bf16_rne(a0.w);
            av[4] = (short)f32_to_bf16_rne(a1.x); av[5] = (short)f32_to_bf16_rne(a1.y);
            av[6] = (short)f32_to_bf16_rne(a1.z); av[7] = (short)f32_to_bf16_rne(a1.w);
            *(bf16x8*)&As[row * 32 + c8 * 8] = av;
            const float* gb = B + (size_t)(bn * 128 + row) * KD + k0 + c8 * 8;
            float4 b0 = *(const float4*)gb;
            float4 b1 = *(const float4*)(gb + 4);
            bf16x8 bv;
            bv[0] = (short)f32_to_bf16_rne(b0.x); bv[1] = (short)f32_to_bf16_rne(b0.y);
            bv[2] = (short)f32_to_bf16_rne(b0.z); bv[3] = (short)f32_to_bf16_rne(b0.w);
            bv[4] = (short)f32_to_bf16_rne(b1.x); bv[5] = (short)f32_to_bf16_rne(b1.y);
            bv[6] = (short)f32_to_bf16_rne(b1.z); bv[7] = (short)f32_to_bf16_rne(b1.w);
            *(bf16x8*)&Bs[row * 32 + c8 * 8] = bv;
        }
        __syncthreads();
        bf16x8 af[4], bfr[4];
        #pragma unroll
        for (int m = 0; m < 4; ++m) af[m] = *(const bf16x8*)&As[(wr * 64 + m * 16 + l15) * 32 + l4 * 8];
        #pragma unroll
        for (int n = 0; n < 4; ++n) bfr[n] = *(const bf16x8*)&Bs[(wc * 64 + n * 16 + l15) * 32 + l4 * 8];
        #pragma unroll
        for (int m = 0; m < 4; ++m)
            #pragma unroll
            for (int n = 0; n < 4; ++n)
                acc[m][n] = __builtin_amdgcn_mfma_f32_16x16x32_bf16(af[m], bfr[n], acc[m][n], 0, 0, 0);
        __syncthreads();
    }
    #pragma unroll
    for (int m = 0; m < 4; ++m) {
        #pragma unroll
        for (int n = 0; n < 4; ++n) {
            int col = bn * 128 + wc * 64 + n * 16 + l15;
            float bias = bih[col] + bhh[col];
            int row0 = bm * 128 + wr * 64 + m * 16 + l4 * 4;
            #pragma unroll
            for (int r = 0; r < 4; ++r)
                C[(size_t)(row0 + r) * NG + col] = acc[m][n][r] + bias;
        }
    }
}

// LLC-coherent (agent-scope) accesses: no cache-wide fences needed anywhere.
__device__ __forceinline__ void st_llc(float* p, float v) {
    __hip_atomic_store(p, v, __ATOMIC_RELAXED, __HIP_MEMORY_SCOPE_AGENT);
}
__device__ __forceinline__ float ld_llc(const float* p) {
    return __hip_atomic_load(p, __ATOMIC_RELAXED, __HIP_MEMORY_SCOPE_AGENT);
}

// ---------------- fence-free flag-array grid barrier ----------------
// Causal chain: gate stores are agent-scope (at LLC) -> __syncthreads drains each
// wave's vmcnt -> t0 sets flag (agent) -> remote poll sees flag -> remote agent
// loads fetch from LLC where the data already lives. No wbl2/inv required.
__device__ __forceinline__ void grid_barrier(unsigned* flags, unsigned gen) {
    __syncthreads();   // all waves' gate stores drained (vmcnt 0) before flag release
    const int t = threadIdx.x;
    if (t == 0) {
        asm volatile("" ::: "memory");
        __hip_atomic_store(&flags[blockIdx.x], gen, __ATOMIC_RELAXED, __HIP_MEMORY_SCOPE_AGENT);
    }
    if (t < 64) {
        const unsigned* f4 = flags + t * 4;
        for (;;) {
            unsigned a = __hip_atomic_load(&f4[0], __ATOMIC_RELAXED, __HIP_MEMORY_SCOPE_AGENT);
            unsigned b = __hip_atomic_load(&f4[1], __ATOMIC_RELAXED, __HIP_MEMORY_SCOPE_AGENT);
            unsigned c = __hip_atomic_load(&f4[2], __ATOMIC_RELAXED, __HIP_MEMORY_SCOPE_AGENT);
            unsigned d = __hip_atomic_load(&f4[3], __ATOMIC_RELAXED, __HIP_MEMORY_SCOPE_AGENT);
            bool ok = (a >= gen) && (b >= gen) && (c >= gen) && (d >= gen);
            if (__all(ok)) break;
            __builtin_amdgcn_s_sleep(1);
        }
    }
    asm volatile("" ::: "memory");  // keep post-barrier loads from hoisting above the poll
    __syncthreads();
}

// ---------------- Persistent recurrence: 1 grid barrier per step ----------------
__global__ __launch_bounds__(512) void lstm_rec(
    const float* __restrict__ xg,          // [SEQ][NG]
    const _Float16* __restrict__ Whh,      // [NG][HD] fp16
    const float* __restrict__ gamma,       // [5][HD]
    const float* __restrict__ beta,        // [5][HD]
    float* __restrict__ gates,             // [2][NG] double-buffered
    unsigned* __restrict__ flags,          // [NB]
    float* __restrict__ yout)              // y[SEQ][HD], hy[HD], cy[HD]
{
    extern __shared__ char smem[];
    _Float16* wlds = (_Float16*)smem;                                  // 32 rows * 2176
    _Float16* hlds = (_Float16*)(smem + (size_t)32 * WROW_STRIDE * 2); // 16 * 136
    float* red   = (float*)((char*)hlds + 16 * PAD_CH * 2);            // 64
    float* stats = red + 64 + 8;                                       // 12

    const int b = blockIdx.x;
    const int t = threadIdx.x;
    const int wave = t >> 6, lane = t & 63;
    const int p = t * 4;                   // this thread's 4 H-positions

    // ---- stage W_hh rows [32b, 32b+32) into LDS (chunk-padded) ----
    for (int idx = t; idx < 32 * 256; idx += NT) {        // 16B granules
        int r = idx >> 8, g = idx & 255;
        f16x8 v = *(const f16x8*)(Whh + (size_t)(b * 32 + r) * HD + g * 8);
        *(f16x8*)&wlds[r * WROW_STRIDE + (g >> 4) * PAD_CH + (g & 15) * 8] = v;
    }
    for (int k = t; k < 16 * PAD_CH; k += NT) hlds[k] = (_Float16)0.0f;

    float4 gm[4], bt[4];
    #pragma unroll
    for (int g = 0; g < 4; ++g) {
        gm[g] = *(const float4*)&gamma[g * HD + p];
        bt[g] = *(const float4*)&beta[g * HD + p];
    }
    float4 gm4 = *(const float4*)&gamma[4 * HD + p];
    float4 bt4 = *(const float4*)&beta[4 * HD + p];

    float* hyout = yout + (size_t)SEQ * HD;
    float* cyout = hyout + HD;
    const float invH = 1.0f / 2048.0f;

    float cprev[4] = {0.f, 0.f, 0.f, 0.f};
    __syncthreads();

    const int row = t >> 4, sub = t & 15;
    const _Float16* wr = wlds + row * WROW_STRIDE + sub * PAD_CH;
    const _Float16* hch = hlds + sub * PAD_CH;
    const int grow = b * 32 + row;

    for (int step = 0; step < SEQ; ++step) {
        float* gb = gates + (size_t)(step & 1) * NG;

        // ---------- GEMV: gates[grow] = xg[step][grow] + W[grow] . h ----------
        float xgv = xg[(size_t)step * NG + grow];
        float acc = 0.0f;
        #pragma unroll
        for (int i = 0; i < 16; ++i) {
            f16x8 wv = *(const f16x8*)(wr + i * 8);
            f16x8 hv = *(const f16x8*)(hch + i * 8);
            const f16x2* w2 = (const f16x2*)&wv;
            const f16x2* h2 = (const f16x2*)&hv;
            acc = __builtin_amdgcn_fdot2(w2[0], h2[0], acc, false);
            acc = __builtin_amdgcn_fdot2(w2[1], h2[1], acc, false);
            acc = __builtin_amdgcn_fdot2(w2[2], h2[2], acc, false);
            acc = __builtin_amdgcn_fdot2(w2[3], h2[3], acc, false);
        }
        #pragma unroll
        for (int off = 1; off < 16; off <<= 1) acc += __shfl_xor(acc, off);
        if (sub == 0) st_llc(&gb[grow], xgv + acc);

        // ---------- single grid barrier (fence-free) ----------
        grid_barrier(flags, (unsigned)(step + 1));

        // ---------- redundant post-phase (identical in every block) ----------
        float gvv[4][4];
        #pragma unroll
        for (int g = 0; g < 4; ++g)
            #pragma unroll
            for (int j = 0; j < 4; ++j)
                gvv[g][j] = ld_llc(&gb[g * HD + p + j]);

        #pragma unroll
        for (int g = 0; g < 4; ++g) {
            float s = gvv[g][0] + gvv[g][1] + gvv[g][2] + gvv[g][3];
            float q = gvv[g][0]*gvv[g][0] + gvv[g][1]*gvv[g][1] + gvv[g][2]*gvv[g][2] + gvv[g][3]*gvv[g][3];
            #pragma unroll
            for (int off = 1; off < 64; off <<= 1) { s += __shfl_xor(s, off); q += __shfl_xor(q, off); }
            if (lane == 0) { red[wave * 8 + g * 2] = s; red[wave * 8 + g * 2 + 1] = q; }
        }
        __syncthreads();
        if (t < 4) {
            float ss = 0.f, qq = 0.f;
            #pragma unroll
            for (int w = 0; w < 8; ++w) { ss += red[w * 8 + t * 2]; qq += red[w * 8 + t * 2 + 1]; }
            float m = ss * invH;
            float v = qq * invH - m * m;
            stats[2 * t] = m; stats[2 * t + 1] = rsqrtf(v + 1e-5f);
        }
        __syncthreads();

        const float m0 = stats[0], r0 = stats[1], m1 = stats[2], r1 = stats[3];
        const float m2 = stats[4], r2 = stats[5], m3 = stats[6], r3 = stats[7];

        float rcv[4], og4[4];
        float s2 = 0.f, q2 = 0.f;
        #pragma unroll
        for (int j = 0; j < 4; ++j) {
            float li = (gvv[0][j] - m0) * r0 * ((const float*)&gm[0])[j] + ((const float*)&bt[0])[j];
            float lf = (gvv[1][j] - m1) * r1 * ((const float*)&gm[1])[j] + ((const float*)&bt[1])[j];
            float lg = (gvv[2][j] - m2) * r2 * ((const float*)&gm[2])[j] + ((const float*)&bt[2])[j];
            float lo = (gvv[3][j] - m3) * r3 * ((const float*)&gm[3])[j] + ((const float*)&bt[3])[j];
            float ig = 1.0f / (1.0f + __expf(-li));
            float fg = 1.0f / (1.0f + __expf(-lf));
            float axg = fabsf(lg);
            float eg = __expf(-2.0f * axg);
            float gg = __builtin_copysignf((1.0f - eg) / (1.0f + eg), lg);
            float og = 1.0f / (1.0f + __expf(-lo));
            float rv = fg * cprev[j] + ig * gg;
            rcv[j] = rv; og4[j] = og;
            s2 += rv; q2 += rv * rv;
        }
        #pragma unroll
        for (int off = 1; off < 64; off <<= 1) { s2 += __shfl_xor(s2, off); q2 += __shfl_xor(q2, off); }
        if (lane == 0) { red[wave * 2] = s2; red[wave * 2 + 1] = q2; }
        __syncthreads();
        if (t == 0) {
            float ss = 0.f, qq = 0.f;
            #pragma unroll
            for (int w = 0; w < 8; ++w) { ss += red[w * 2]; qq += red[w * 2 + 1]; }
            float m = ss * invH;
            float v = qq * invH - m * m;
            stats[8] = m; stats[9] = rsqrtf(v + 1e-5f);
        }
        __syncthreads();
        const float mc = stats[8], rc = stats[9];

        float hvf[4], lcf[4];
        f16x4 hh;
        #pragma unroll
        for (int j = 0; j < 4; ++j) {
            float lc = (rcv[j] - mc) * rc * ((const float*)&gm4)[j] + ((const float*)&bt4)[j];
            cprev[j] = lc;
            float ax = fabsf(lc);
            float e = __expf(-2.0f * ax);
            float th = __builtin_copysignf((1.0f - e) / (1.0f + e), lc);
            float hv = og4[j] * th;
            hvf[j] = hv; lcf[j] = lc;
            hh[j] = (_Float16)hv;
        }
        *(f16x4*)&hlds[(p >> 7) * PAD_CH + (p & 127)] = hh;

        if ((t >> 1) == b) {   // this block owns global slice [8b, 8b+8)
            float4 ho = {hvf[0], hvf[1], hvf[2], hvf[3]};
            *(float4*)&yout[(size_t)step * HD + p] = ho;
            if (step == SEQ - 1) {
                *(float4*)&hyout[p] = ho;
                float4 co = {lcf[0], lcf[1], lcf[2], lcf[3]};
                *(float4*)&cyout[p] = co;
            }
        }
        __syncthreads();   // hlds ready for next GEMV
    }
}

extern "C" void kernel_launch(void* const* d_in, const int* in_sizes, int n_in,
                              void* d_out, int out_size, void* d_ws, size_t ws_size,
                              hipStream_t stream) {
    const float* x   = (const float*)d_in[0];
    const float* wih = (const float*)d_in[1];
    const float* whh = (const float*)d_in[2];
    const float* bih = (const float*)d_in[3];
    const float* bhh = (const float*)d_in[4];
    const float* gam = (const float*)d_in[5];
    const float* bet = (const float*)d_in[6];
    float* out = (float*)d_out;

    char* ws = (char*)d_ws;
    size_t off = 0;
    auto carve = [&](size_t bytes) -> void* {
        void* pp = ws + off;
        off += (bytes + 255) & ~(size_t)255;
        return pp;
    };
    float* xg      = (float*)carve(sizeof(float) * (size_t)SEQ * NG);      // 64 MB
    _Float16* whhf = (_Float16*)carve(sizeof(_Float16) * (size_t)NG * HD); // 32 MB
    float* gates   = (float*)carve(sizeof(float) * 2 * NG);
    unsigned* flags = (unsigned*)carve(sizeof(unsigned) * NB);

    cvt_f16_kernel<<<2048, 256, 0, stream>>>(whh, whhf, NG * HD);
    dim3 ggrid(16, 64);
    gemm_xg<<<ggrid, 256, 0, stream>>>(x, wih, bih, bhh, xg);
    hipMemsetAsync(flags, 0, sizeof(unsigned) * NB, stream);

    size_t ldsbytes = (size_t)32 * WROW_STRIDE * 2 + (size_t)16 * PAD_CH * 2 + (64 + 8 + 12) * 4;
    hipFuncSetAttribute((const void*)lstm_rec, hipFuncAttributeMaxDynamicSharedMemorySize, (int)ldsbytes);

    void* args[] = { (void*)&xg, (void*)&whhf, (void*)&gam, (void*)&bet,
                     (void*)&gates, (void*)&flags, (void*)&out };
    hipLaunchCooperativeKernel((void*)lstm_rec, dim3(NB), dim3(NT), args, (unsigned)ldsbytes, stream);
}

// Round 4
// 16595.663 us; speedup vs baseline: 7.2193x; 1.1618x over previous
//
#include <hip/hip_runtime.h>

typedef float f32x4 __attribute__((ext_vector_type(4)));
typedef short bf16x8 __attribute__((ext_vector_type(8)));
typedef _Float16 f16x2 __attribute__((ext_vector_type(2)));
typedef _Float16 f16x4 __attribute__((ext_vector_type(4)));
typedef _Float16 f16x8 __attribute__((ext_vector_type(8)));

#define SEQ 2048
#define HD 2048
#define NG 8192
#define KD 2048
#define NB 256
#define NT 512
#define PAD_CH 136                    // fp16 per 128-elem chunk incl. 8 pad
#define WROW_STRIDE (16 * PAD_CH)     // 2176 fp16 per W row in LDS

__device__ __forceinline__ unsigned short f32_to_bf16_rne(float f) {
    unsigned int u = __float_as_uint(f);
    u += 0x7FFFu + ((u >> 16) & 1u);
    return (unsigned short)(u >> 16);
}

__global__ void cvt_f16_kernel(const float* __restrict__ in, _Float16* __restrict__ out, int n) {
    for (int i = blockIdx.x * blockDim.x + threadIdx.x; i < n; i += gridDim.x * blockDim.x)
        out[i] = (_Float16)in[i];
}

// ---------------- GEMM: xg[s][g] = sum_k x[s][k] * w_ih[g][k] + b_ih[g] + b_hh[g] ----------------
__global__ __launch_bounds__(256) void gemm_xg(
    const float* __restrict__ A,    // x   [2048][2048]
    const float* __restrict__ B,    // w_ih[8192][2048]
    const float* __restrict__ bih, const float* __restrict__ bhh,
    float* __restrict__ C)          // xg  [2048][8192]
{
    __shared__ unsigned short As[128 * 32];
    __shared__ unsigned short Bs[128 * 32];
    const int tid = threadIdx.x;
    const int bm = blockIdx.x, bn = blockIdx.y;
    const int wave = tid >> 6, lane = tid & 63;
    const int wr = wave >> 1, wc = wave & 1;
    const int l15 = lane & 15, l4 = lane >> 4;

    f32x4 acc[4][4];
    #pragma unroll
    for (int i = 0; i < 4; ++i)
        #pragma unroll
        for (int j = 0; j < 4; ++j) {
            f32x4 z = {0.f, 0.f, 0.f, 0.f};
            acc[i][j] = z;
        }

    for (int k0 = 0; k0 < KD; k0 += 32) {
        #pragma unroll
        for (int i = 0; i < 2; ++i) {
            int idx = tid + i * 256;
            int row = idx >> 2, c8 = idx & 3;
            const float* ga = A + (size_t)(bm * 128 + row) * KD + k0 + c8 * 8;
            float4 a0 = *(const float4*)ga;
            float4 a1 = *(const float4*)(ga + 4);
            bf16x8 av;
            av[0] = (short)f32_to_bf16_rne(a0.x); av[1] = (short)f32_to_bf16_rne(a0.y);
            av[2] = (short)f32_to_bf16_rne(a0.z); av[3] = (short)f32_to_bf16_rne(a0.w);
            av[4] = (short)f32_to_bf16_rne(a1.x); av[5] = (short)f32_to_bf16_rne(a1.y);
            av[6] = (short)f32_to_bf16_rne(a1.z); av[7] = (short)f32_to_bf16_rne(a1.w);
            *(bf16x8*)&As[row * 32 + c8 * 8] = av;
            const float* gb = B + (size_t)(bn * 128 + row) * KD + k0 + c8 * 8;
            float4 b0 = *(const float4*)gb;
            float4 b1 = *(const float4*)(gb + 4);
            bf16x8 bv;
            bv[0] = (short)f32_to_bf16_rne(b0.x); bv[1] = (short)f32_to_bf16_rne(b0.y);
            bv[2] = (short)f32_to_bf16_rne(b0.z); bv[3] = (short)f32_to_bf16_rne(b0.w);
            bv[4] = (short)f32_to_bf16_rne(b1.x); bv[5] = (short)f32_to_bf16_rne(b1.y);
            bv[6] = (short)f32_to_bf16_rne(b1.z); bv[7] = (short)f32_to_bf16_rne(b1.w);
            *(bf16x8*)&Bs[row * 32 + c8 * 8] = bv;
        }
        __syncthreads();
        bf16x8 af[4], bfr[4];
        #pragma unroll
        for (int m = 0; m < 4; ++m) af[m] = *(const bf16x8*)&As[(wr * 64 + m * 16 + l15) * 32 + l4 * 8];
        #pragma unroll
        for (int n = 0; n < 4; ++n) bfr[n] = *(const bf16x8*)&Bs[(wc * 64 + n * 16 + l15) * 32 + l4 * 8];
        #pragma unroll
        for (int m = 0; m < 4; ++m)
            #pragma unroll
            for (int n = 0; n < 4; ++n)
                acc[m][n] = __builtin_amdgcn_mfma_f32_16x16x32_bf16(af[m], bfr[n], acc[m][n], 0, 0, 0);
        __syncthreads();
    }
    #pragma unroll
    for (int m = 0; m < 4; ++m) {
        #pragma unroll
        for (int n = 0; n < 4; ++n) {
            int col = bn * 128 + wc * 64 + n * 16 + l15;
            float bias = bih[col] + bhh[col];
            int row0 = bm * 128 + wr * 64 + m * 16 + l4 * 4;
            #pragma unroll
            for (int r = 0; r < 4; ++r)
                C[(size_t)(row0 + r) * NG + col] = acc[m][n][r] + bias;
        }
    }
}

// LLC-coherent (agent-scope) accesses: no cache-wide fences needed anywhere.
__device__ __forceinline__ void st_llc(float* p, float v) {
    __hip_atomic_store(p, v, __ATOMIC_RELAXED, __HIP_MEMORY_SCOPE_AGENT);
}

// 4x coherent 16B loads, issued back-to-back, one waitcnt (LLC latency overlapped).
__device__ __forceinline__ void ld_llc_4x4(const float* p0, const float* p1,
                                           const float* p2, const float* p3,
                                           f32x4& a, f32x4& b, f32x4& c, f32x4& d) {
    asm volatile(
        "global_load_dwordx4 %0, %4, off sc0 sc1\n\t"
        "global_load_dwordx4 %1, %5, off sc0 sc1\n\t"
        "global_load_dwordx4 %2, %6, off sc0 sc1\n\t"
        "global_load_dwordx4 %3, %7, off sc0 sc1\n\t"
        "s_waitcnt vmcnt(0)"
        : "=&v"(a), "=&v"(b), "=&v"(c), "=&v"(d)
        : "v"(p0), "v"(p1), "v"(p2), "v"(p3)
        : "memory");
}

// ---------------- counter+release grid barrier ----------------
// Arrival: one agent-scope atomic add per block on a single LLC line (pipelined
// near-memory atomics, no poll storm). The 256th arriver of generation `gen`
// sees old == gen*NB-1 in its returned value (no extra observation hop) and
// release-stores gen. All other blocks poll ONE read-shared line with 1 thread.
// Gate stores are agent-scope and drained (vmcnt) by __syncthreads before the
// arrival add, so release implies all gates are at the coherence point.
__device__ __forceinline__ void grid_barrier(unsigned* cnt, unsigned* release, unsigned gen) {
    __syncthreads();
    if (threadIdx.x == 0) {
        asm volatile("" ::: "memory");
        unsigned old = __hip_atomic_fetch_add(cnt, 1u, __ATOMIC_RELAXED, __HIP_MEMORY_SCOPE_AGENT);
        if (old == gen * NB - 1u) {
            __hip_atomic_store(release, gen, __ATOMIC_RELAXED, __HIP_MEMORY_SCOPE_AGENT);
        } else {
            while (__hip_atomic_load(release, __ATOMIC_RELAXED, __HIP_MEMORY_SCOPE_AGENT) < gen)
                __builtin_amdgcn_s_sleep(1);
        }
        asm volatile("" ::: "memory");
    }
    __syncthreads();
}

// ---------------- Persistent recurrence: 1 grid barrier per step ----------------
__global__ __launch_bounds__(512) void lstm_rec(
    const float* __restrict__ xg,          // [SEQ][NG]
    const _Float16* __restrict__ Whh,      // [NG][HD] fp16
    const float* __restrict__ gamma,       // [5][HD]
    const float* __restrict__ beta,        // [5][HD]
    float* __restrict__ gates,             // [2][NG] double-buffered
    unsigned* __restrict__ barctl,         // [0]=counter, [32]=release (separate lines)
    float* __restrict__ yout)              // y[SEQ][HD], hy[HD], cy[HD]
{
    extern __shared__ char smem[];
    _Float16* wlds = (_Float16*)smem;                                  // 32 rows * 2176
    _Float16* hlds = (_Float16*)(smem + (size_t)32 * WROW_STRIDE * 2); // 16 * 136
    float* red   = (float*)((char*)hlds + 16 * PAD_CH * 2);            // 64
    float* stats = red + 64 + 8;                                       // 12

    const int b = blockIdx.x;
    const int t = threadIdx.x;
    const int wave = t >> 6, lane = t & 63;
    const int p = t * 4;                   // this thread's 4 H-positions

    unsigned* cnt = barctl;
    unsigned* release = barctl + 32;

    // ---- stage W_hh rows [32b, 32b+32) into LDS (chunk-padded) ----
    for (int idx = t; idx < 32 * 256; idx += NT) {        // 16B granules
        int r = idx >> 8, g = idx & 255;
        f16x8 v = *(const f16x8*)(Whh + (size_t)(b * 32 + r) * HD + g * 8);
        *(f16x8*)&wlds[r * WROW_STRIDE + (g >> 4) * PAD_CH + (g & 15) * 8] = v;
    }
    for (int k = t; k < 16 * PAD_CH; k += NT) hlds[k] = (_Float16)0.0f;

    float4 gm[4], bt[4];
    #pragma unroll
    for (int g = 0; g < 4; ++g) {
        gm[g] = *(const float4*)&gamma[g * HD + p];
        bt[g] = *(const float4*)&beta[g * HD + p];
    }
    float4 gm4 = *(const float4*)&gamma[4 * HD + p];
    float4 bt4 = *(const float4*)&beta[4 * HD + p];

    float* hyout = yout + (size_t)SEQ * HD;
    float* cyout = hyout + HD;
    const float invH = 1.0f / 2048.0f;

    float cprev[4] = {0.f, 0.f, 0.f, 0.f};
    __syncthreads();

    const int row = t >> 4, sub = t & 15;
    const _Float16* wr = wlds + row * WROW_STRIDE + sub * PAD_CH;
    const _Float16* hch = hlds + sub * PAD_CH;
    const int grow = b * 32 + row;

    for (int step = 0; step < SEQ; ++step) {
        float* gb = gates + (size_t)(step & 1) * NG;

        // ---------- GEMV: gates[grow] = xg[step][grow] + W[grow] . h ----------
        float xgv = xg[(size_t)step * NG + grow];
        float acc = 0.0f;
        #pragma unroll
        for (int i = 0; i < 16; ++i) {
            f16x8 wv = *(const f16x8*)(wr + i * 8);
            f16x8 hv = *(const f16x8*)(hch + i * 8);
            const f16x2* w2 = (const f16x2*)&wv;
            const f16x2* h2 = (const f16x2*)&hv;
            acc = __builtin_amdgcn_fdot2(w2[0], h2[0], acc, false);
            acc = __builtin_amdgcn_fdot2(w2[1], h2[1], acc, false);
            acc = __builtin_amdgcn_fdot2(w2[2], h2[2], acc, false);
            acc = __builtin_amdgcn_fdot2(w2[3], h2[3], acc, false);
        }
        #pragma unroll
        for (int off = 1; off < 16; off <<= 1) acc += __shfl_xor(acc, off);
        if (sub == 0) st_llc(&gb[grow], xgv + acc);

        // ---------- single grid barrier ----------
        grid_barrier(cnt, release, (unsigned)(step + 1));

        // ---------- redundant post-phase (identical in every block) ----------
        f32x4 gq[4];
        ld_llc_4x4(&gb[0 * HD + p], &gb[1 * HD + p], &gb[2 * HD + p], &gb[3 * HD + p],
                   gq[0], gq[1], gq[2], gq[3]);
        float gvv[4][4];
        #pragma unroll
        for (int g = 0; g < 4; ++g)
            #pragma unroll
            for (int j = 0; j < 4; ++j)
                gvv[g][j] = gq[g][j];

        #pragma unroll
        for (int g = 0; g < 4; ++g) {
            float s = gvv[g][0] + gvv[g][1] + gvv[g][2] + gvv[g][3];
            float q = gvv[g][0]*gvv[g][0] + gvv[g][1]*gvv[g][1] + gvv[g][2]*gvv[g][2] + gvv[g][3]*gvv[g][3];
            #pragma unroll
            for (int off = 1; off < 64; off <<= 1) { s += __shfl_xor(s, off); q += __shfl_xor(q, off); }
            if (lane == 0) { red[wave * 8 + g * 2] = s; red[wave * 8 + g * 2 + 1] = q; }
        }
        __syncthreads();
        if (t < 4) {
            float ss = 0.f, qq = 0.f;
            #pragma unroll
            for (int w = 0; w < 8; ++w) { ss += red[w * 8 + t * 2]; qq += red[w * 8 + t * 2 + 1]; }
            float m = ss * invH;
            float v = qq * invH - m * m;
            stats[2 * t] = m; stats[2 * t + 1] = rsqrtf(v + 1e-5f);
        }
        __syncthreads();

        const float m0 = stats[0], r0 = stats[1], m1 = stats[2], r1 = stats[3];
        const float m2 = stats[4], r2 = stats[5], m3 = stats[6], r3 = stats[7];

        float rcv[4], og4[4];
        float s2 = 0.f, q2 = 0.f;
        #pragma unroll
        for (int j = 0; j < 4; ++j) {
            float li = (gvv[0][j] - m0) * r0 * ((const float*)&gm[0])[j] + ((const float*)&bt[0])[j];
            float lf = (gvv[1][j] - m1) * r1 * ((const float*)&gm[1])[j] + ((const float*)&bt[1])[j];
            float lg = (gvv[2][j] - m2) * r2 * ((const float*)&gm[2])[j] + ((const float*)&bt[2])[j];
            float lo = (gvv[3][j] - m3) * r3 * ((const float*)&gm[3])[j] + ((const float*)&bt[3])[j];
            float ig = 1.0f / (1.0f + __expf(-li));
            float fg = 1.0f / (1.0f + __expf(-lf));
            float axg = fabsf(lg);
            float eg = __expf(-2.0f * axg);
            float gg = __builtin_copysignf((1.0f - eg) / (1.0f + eg), lg);
            float og = 1.0f / (1.0f + __expf(-lo));
            float rv = fg * cprev[j] + ig * gg;
            rcv[j] = rv; og4[j] = og;
            s2 += rv; q2 += rv * rv;
        }
        #pragma unroll
        for (int off = 1; off < 64; off <<= 1) { s2 += __shfl_xor(s2, off); q2 += __shfl_xor(q2, off); }
        if (lane == 0) { red[wave * 2] = s2; red[wave * 2 + 1] = q2; }
        __syncthreads();
        if (t == 0) {
            float ss = 0.f, qq = 0.f;
            #pragma unroll
            for (int w = 0; w < 8; ++w) { ss += red[w * 2]; qq += red[w * 2 + 1]; }
            float m = ss * invH;
            float v = qq * invH - m * m;
            stats[8] = m; stats[9] = rsqrtf(v + 1e-5f);
        }
        __syncthreads();
        const float mc = stats[8], rc = stats[9];

        float hvf[4], lcf[4];
        f16x4 hh;
        #pragma unroll
        for (int j = 0; j < 4; ++j) {
            float lc = (rcv[j] - mc) * rc * ((const float*)&gm4)[j] + ((const float*)&bt4)[j];
            cprev[j] = lc;
            float ax = fabsf(lc);
            float e = __expf(-2.0f * ax);
            float th = __builtin_copysignf((1.0f - e) / (1.0f + e), lc);
            float hv = og4[j] * th;
            hvf[j] = hv; lcf[j] = lc;
            hh[j] = (_Float16)hv;
        }
        *(f16x4*)&hlds[(p >> 7) * PAD_CH + (p & 127)] = hh;

        if ((t >> 1) == b) {   // this block owns global slice [8b, 8b+8)
            float4 ho = {hvf[0], hvf[1], hvf[2], hvf[3]};
            *(float4*)&yout[(size_t)step * HD + p] = ho;
            if (step == SEQ - 1) {
                *(float4*)&hyout[p] = ho;
                float4 co = {lcf[0], lcf[1], lcf[2], lcf[3]};
                *(float4*)&cyout[p] = co;
            }
        }
        __syncthreads();   // hlds ready for next GEMV
    }
}

extern "C" void kernel_launch(void* const* d_in, const int* in_sizes, int n_in,
                              void* d_out, int out_size, void* d_ws, size_t ws_size,
                              hipStream_t stream) {
    const float* x   = (const float*)d_in[0];
    const float* wih = (const float*)d_in[1];
    const float* whh = (const float*)d_in[2];
    const float* bih = (const float*)d_in[3];
    const float* bhh = (const float*)d_in[4];
    const float* gam = (const float*)d_in[5];
    const float* bet = (const float*)d_in[6];
    float* out = (float*)d_out;

    char* ws = (char*)d_ws;
    size_t off = 0;
    auto carve = [&](size_t bytes) -> void* {
        void* pp = ws + off;
        off += (bytes + 255) & ~(size_t)255;
        return pp;
    };
    float* xg      = (float*)carve(sizeof(float) * (size_t)SEQ * NG);      // 64 MB
    _Float16* whhf = (_Float16*)carve(sizeof(_Float16) * (size_t)NG * HD); // 32 MB
    float* gates   = (float*)carve(sizeof(float) * 2 * NG);
    unsigned* barctl = (unsigned*)carve(sizeof(unsigned) * 64);            // cnt @0, release @32

    cvt_f16_kernel<<<2048, 256, 0, stream>>>(whh, whhf, NG * HD);
    dim3 ggrid(16, 64);
    gemm_xg<<<ggrid, 256, 0, stream>>>(x, wih, bih, bhh, xg);
    hipMemsetAsync(barctl, 0, sizeof(unsigned) * 64, stream);

    size_t ldsbytes = (size_t)32 * WROW_STRIDE * 2 + (size_t)16 * PAD_CH * 2 + (64 + 8 + 12) * 4;
    hipFuncSetAttribute((const void*)lstm_rec, hipFuncAttributeMaxDynamicSharedMemorySize, (int)ldsbytes);

    void* args[] = { (void*)&xg, (void*)&whhf, (void*)&gam, (void*)&bet,
                     (void*)&gates, (void*)&barctl, (void*)&out };
    hipLaunchCooperativeKernel((void*)lstm_rec, dim3(NB), dim3(NT), args, (unsigned)ldsbytes, stream);
}

// Round 5
// 13117.360 us; speedup vs baseline: 9.1336x; 1.2652x over previous
//
#include <hip/hip_runtime.h>

typedef float f32x4 __attribute__((ext_vector_type(4)));
typedef short bf16x8 __attribute__((ext_vector_type(8)));
typedef _Float16 f16x2 __attribute__((ext_vector_type(2)));
typedef _Float16 f16x4 __attribute__((ext_vector_type(4)));
typedef _Float16 f16x8 __attribute__((ext_vector_type(8)));

#define SEQ 2048
#define HD 2048
#define NG 8192
#define KD 2048
#define NB 256
#define NT 512
#define PAD_CH 136                    // fp16 per 128-elem h-chunk incl. 8 pad (272B stride)

__device__ __forceinline__ unsigned short f32_to_bf16_rne(float f) {
    unsigned int u = __float_as_uint(f);
    u += 0x7FFFu + ((u >> 16) & 1u);
    return (unsigned short)(u >> 16);
}

__global__ void cvt_f16_kernel(const float* __restrict__ in, _Float16* __restrict__ out, int n) {
    for (int i = blockIdx.x * blockDim.x + threadIdx.x; i < n; i += gridDim.x * blockDim.x)
        out[i] = (_Float16)in[i];
}

// ---------------- GEMM: xg[s][g] = sum_k x[s][k] * w_ih[g][k] + b_ih[g] + b_hh[g] ----------------
__global__ __launch_bounds__(256) void gemm_xg(
    const float* __restrict__ A,    // x   [2048][2048]
    const float* __restrict__ B,    // w_ih[8192][2048]
    const float* __restrict__ bih, const float* __restrict__ bhh,
    float* __restrict__ C)          // xg  [2048][8192]
{
    __shared__ unsigned short As[128 * 32];
    __shared__ unsigned short Bs[128 * 32];
    const int tid = threadIdx.x;
    const int bm = blockIdx.x, bn = blockIdx.y;
    const int wave = tid >> 6, lane = tid & 63;
    const int wr = wave >> 1, wc = wave & 1;
    const int l15 = lane & 15, l4 = lane >> 4;

    f32x4 acc[4][4];
    #pragma unroll
    for (int i = 0; i < 4; ++i)
        #pragma unroll
        for (int j = 0; j < 4; ++j) {
            f32x4 z = {0.f, 0.f, 0.f, 0.f};
            acc[i][j] = z;
        }

    for (int k0 = 0; k0 < KD; k0 += 32) {
        #pragma unroll
        for (int i = 0; i < 2; ++i) {
            int idx = tid + i * 256;
            int row = idx >> 2, c8 = idx & 3;
            const float* ga = A + (size_t)(bm * 128 + row) * KD + k0 + c8 * 8;
            float4 a0 = *(const float4*)ga;
            float4 a1 = *(const float4*)(ga + 4);
            bf16x8 av;
            av[0] = (short)f32_to_bf16_rne(a0.x); av[1] = (short)f32_to_bf16_rne(a0.y);
            av[2] = (short)f32_to_bf16_rne(a0.z); av[3] = (short)f32_to_bf16_rne(a0.w);
            av[4] = (short)f32_to_bf16_rne(a1.x); av[5] = (short)f32_to_bf16_rne(a1.y);
            av[6] = (short)f32_to_bf16_rne(a1.z); av[7] = (short)f32_to_bf16_rne(a1.w);
            *(bf16x8*)&As[row * 32 + c8 * 8] = av;
            const float* gb = B + (size_t)(bn * 128 + row) * KD + k0 + c8 * 8;
            float4 b0 = *(const float4*)gb;
            float4 b1 = *(const float4*)(gb + 4);
            bf16x8 bv;
            bv[0] = (short)f32_to_bf16_rne(b0.x); bv[1] = (short)f32_to_bf16_rne(b0.y);
            bv[2] = (short)f32_to_bf16_rne(b0.z); bv[3] = (short)f32_to_bf16_rne(b0.w);
            bv[4] = (short)f32_to_bf16_rne(b1.x); bv[5] = (short)f32_to_bf16_rne(b1.y);
            bv[6] = (short)f32_to_bf16_rne(b1.z); bv[7] = (short)f32_to_bf16_rne(b1.w);
            *(bf16x8*)&Bs[row * 32 + c8 * 8] = bv;
        }
        __syncthreads();
        bf16x8 af[4], bfr[4];
        #pragma unroll
        for (int m = 0; m < 4; ++m) af[m] = *(const bf16x8*)&As[(wr * 64 + m * 16 + l15) * 32 + l4 * 8];
        #pragma unroll
        for (int n = 0; n < 4; ++n) bfr[n] = *(const bf16x8*)&Bs[(wc * 64 + n * 16 + l15) * 32 + l4 * 8];
        #pragma unroll
        for (int m = 0; m < 4; ++m)
            #pragma unroll
            for (int n = 0; n < 4; ++n)
                acc[m][n] = __builtin_amdgcn_mfma_f32_16x16x32_bf16(af[m], bfr[n], acc[m][n], 0, 0, 0);
        __syncthreads();
    }
    #pragma unroll
    for (int m = 0; m < 4; ++m) {
        #pragma unroll
        for (int n = 0; n < 4; ++n) {
            int col = bn * 128 + wc * 64 + n * 16 + l15;
            float bias = bih[col] + bhh[col];
            int row0 = bm * 128 + wr * 64 + m * 16 + l4 * 4;
            #pragma unroll
            for (int r = 0; r < 4; ++r)
                C[(size_t)(row0 + r) * NG + col] = acc[m][n][r] + bias;
        }
    }
}

// ---- LLC-coherent primitives (agent scope; no cache-wide fences anywhere) ----
__device__ __forceinline__ void st_llc16(float* p, f32x4 v) {
    asm volatile("global_store_dwordx4 %0, %1, off sc0 sc1" :: "v"(p), "v"(v) : "memory");
}
__device__ __forceinline__ void ld_llc_4x4(const float* p0, const float* p1,
                                           const float* p2, const float* p3,
                                           f32x4& a, f32x4& b, f32x4& c, f32x4& d) {
    asm volatile(
        "global_load_dwordx4 %0, %4, off sc0 sc1\n\t"
        "global_load_dwordx4 %1, %5, off sc0 sc1\n\t"
        "global_load_dwordx4 %2, %6, off sc0 sc1\n\t"
        "global_load_dwordx4 %3, %7, off sc0 sc1\n\t"
        "s_waitcnt vmcnt(0)"
        : "=&v"(a), "=&v"(b), "=&v"(c), "=&v"(d)
        : "v"(p0), "v"(p1), "v"(p2), "v"(p3)
        : "memory");
}

// barctl layout (unsigned, 64-word = 256B spacing):
//   [g*64]        g=0..7   group arrival counters (32 blocks each)
//   [8*64]                 root counter (8 groups)
//   [(9+g)*64]    g=0..7   relay release lines (polled per group)
#define ROOT_OFF (8 * 64)
#define RELAY_OFF (9 * 64)

// ---------------- Persistent recurrence: 1 tree-barrier per step ----------------
// Per step: GEMV (W in VGPRs, h in LDS broadcast) -> packed gate store (LLC) ->
// syncthreads (drain) -> t0 tree arrival -> all waves poll relay ->
// redundant post-phase: gate loads, LN stats (wave shfl + LDS partials + local
// finalize), activations, c-update in regs, cy stats, h -> LDS.
__global__ __launch_bounds__(512, 2) void lstm_rec(
    const float* __restrict__ xg,          // [SEQ][NG]
    const _Float16* __restrict__ Whh,      // [NG][HD] fp16
    const float* __restrict__ gamma,       // [5][HD]
    const float* __restrict__ beta,        // [5][HD]
    float* __restrict__ gates,             // [2][NG] double-buffered
    unsigned* __restrict__ barctl,
    float* __restrict__ yout)              // y[SEQ][HD], hy[HD], cy[HD]
{
    __shared__ _Float16 hlds[16 * PAD_CH];
    __shared__ __align__(16) float red[64];   // [s: g*8+w | q: 32+g*8+w]
    __shared__ __align__(16) float red2[16];  // [s: w | q: 8+w]

    const int b = blockIdx.x;
    const int t = threadIdx.x;
    const int wave = t >> 6, lane = t & 63;
    const int p = t * 4;                   // this thread's 4 H-positions

    unsigned* grpcnt = barctl + (b >> 5) * 64;
    unsigned* rootcnt = barctl + ROOT_OFF;
    unsigned* relay = barctl + RELAY_OFF + (b >> 5) * 64;

    const int row = t >> 4, sub = t & 15;  // GEMV: row 0..31, 128-col chunk
    const int grow = b * 32 + row;

    // ---- W strip -> 64 VGPRs (one-time) ----
    f16x8 wreg[16];
    {
        const _Float16* wsrc = Whh + (size_t)grow * HD + sub * 128;
        #pragma unroll
        for (int i = 0; i < 16; ++i) wreg[i] = *(const f16x8*)(wsrc + i * 8);
    }
    for (int k = t; k < 16 * PAD_CH; k += NT) hlds[k] = (_Float16)0.0f;

    float4 gm[4], bt[4];
    #pragma unroll
    for (int g = 0; g < 4; ++g) {
        gm[g] = *(const float4*)&gamma[g * HD + p];
        bt[g] = *(const float4*)&beta[g * HD + p];
    }
    float4 gm4 = *(const float4*)&gamma[4 * HD + p];
    float4 bt4 = *(const float4*)&beta[4 * HD + p];

    float* hyout = yout + (size_t)SEQ * HD;
    float* cyout = hyout + HD;
    const float invH = 1.0f / 2048.0f;

    float cprev[4] = {0.f, 0.f, 0.f, 0.f};

    // lane0 of wave w holds xg float4 for rows b*32 + 4w .. +3
    float4 xg4 = {0.f, 0.f, 0.f, 0.f};
    if (lane == 0) xg4 = *(const float4*)(xg + b * 32 + wave * 4);

    const _Float16* hch = hlds + sub * PAD_CH;
    __syncthreads();

    for (int step = 0; step < SEQ; ++step) {
        float* gb = gates + (size_t)(step & 1) * NG;
        const unsigned gen = (unsigned)(step + 1);

        // ---------- GEMV from registers; h via LDS broadcast ----------
        float a0 = 0.f, a1 = 0.f, a2 = 0.f, a3 = 0.f;
        #pragma unroll
        for (int i = 0; i < 16; ++i) {
            f16x8 hv = *(const f16x8*)(hch + i * 8);
            const f16x2* w2 = (const f16x2*)&wreg[i];
            const f16x2* h2 = (const f16x2*)&hv;
            float* ac = (i & 3) == 0 ? &a0 : (i & 3) == 1 ? &a1 : (i & 3) == 2 ? &a2 : &a3;
            float x = *ac;
            x = __builtin_amdgcn_fdot2(w2[0], h2[0], x, false);
            x = __builtin_amdgcn_fdot2(w2[1], h2[1], x, false);
            x = __builtin_amdgcn_fdot2(w2[2], h2[2], x, false);
            x = __builtin_amdgcn_fdot2(w2[3], h2[3], x, false);
            *ac = x;
        }
        float r = (a0 + a1) + (a2 + a3);
        #pragma unroll
        for (int off = 1; off < 16; off <<= 1) r += __shfl_xor(r, off);
        // gather 4 row-sums of this wave to lane0, pack, one coherent 16B store
        float r1 = __shfl(r, 16), r2 = __shfl(r, 32), r3 = __shfl(r, 48);
        if (lane == 0) {
            f32x4 gv4 = {r + xg4.x, r1 + xg4.y, r2 + xg4.z, r3 + xg4.w};
            st_llc16(&gb[b * 32 + wave * 4], gv4);
        }

        __syncthreads();   // drains all waves' gate stores (vmcnt) before arrival

        // ---------- tree arrival (t0 only) ----------
        if (t == 0) {
            asm volatile("" ::: "memory");
            unsigned o1 = __hip_atomic_fetch_add(grpcnt, 1u, __ATOMIC_RELAXED, __HIP_MEMORY_SCOPE_AGENT);
            if (o1 == gen * 32u - 1u) {
                unsigned o2 = __hip_atomic_fetch_add(rootcnt, 1u, __ATOMIC_RELAXED, __HIP_MEMORY_SCOPE_AGENT);
                if (o2 == gen * 8u - 1u) {
                    #pragma unroll
                    for (int g = 0; g < 8; ++g)
                        __hip_atomic_store(barctl + RELAY_OFF + g * 64, gen,
                                           __ATOMIC_RELAXED, __HIP_MEMORY_SCOPE_AGENT);
                }
            }
        }
        // ---------- wave self-release: poll this group's relay line ----------
        for (;;) {
            unsigned rv = __hip_atomic_load(relay, __ATOMIC_RELAXED, __HIP_MEMORY_SCOPE_AGENT);
            if (rv >= gen) break;
            __builtin_amdgcn_s_sleep(1);
        }
        asm volatile("" ::: "memory");

        // prefetch next step's xg while the post-phase runs
        if (lane == 0 && step + 1 < SEQ)
            xg4 = *(const float4*)(xg + (size_t)(step + 1) * NG + b * 32 + wave * 4);

        // ---------- redundant post-phase ----------
        f32x4 gq[4];
        ld_llc_4x4(&gb[0 * HD + p], &gb[1 * HD + p], &gb[2 * HD + p], &gb[3 * HD + p],
                   gq[0], gq[1], gq[2], gq[3]);

        #pragma unroll
        for (int g = 0; g < 4; ++g) {
            float s = gq[g][0] + gq[g][1] + gq[g][2] + gq[g][3];
            float q = gq[g][0]*gq[g][0] + gq[g][1]*gq[g][1] + gq[g][2]*gq[g][2] + gq[g][3]*gq[g][3];
            #pragma unroll
            for (int off = 1; off < 64; off <<= 1) { s += __shfl_xor(s, off); q += __shfl_xor(q, off); }
            if (lane == 0) { red[g * 8 + wave] = s; red[32 + g * 8 + wave] = q; }
        }
        __syncthreads();   // [A] partials visible

        // every thread finalizes stats locally (b128 broadcast reads, no 2nd sync)
        float mg[4], rg[4];
        {
            const f32x4* r4 = (const f32x4*)red;
            #pragma unroll
            for (int g = 0; g < 4; ++g) {
                f32x4 sa = r4[g * 2], sb = r4[g * 2 + 1];
                f32x4 qa = r4[8 + g * 2], qb = r4[8 + g * 2 + 1];
                float s = ((sa[0] + sa[1]) + (sa[2] + sa[3])) + ((sb[0] + sb[1]) + (sb[2] + sb[3]));
                float q = ((qa[0] + qa[1]) + (qa[2] + qa[3])) + ((qb[0] + qb[1]) + (qb[2] + qb[3]));
                float m = s * invH;
                mg[g] = m;
                rg[g] = rsqrtf(q * invH - m * m + 1e-5f);
            }
        }

        float rcv[4], og4[4];
        float s2 = 0.f, q2 = 0.f;
        #pragma unroll
        for (int j = 0; j < 4; ++j) {
            float li = (gq[0][j] - mg[0]) * rg[0] * ((const float*)&gm[0])[j] + ((const float*)&bt[0])[j];
            float lf = (gq[1][j] - mg[1]) * rg[1] * ((const float*)&gm[1])[j] + ((const float*)&bt[1])[j];
            float lg = (gq[2][j] - mg[2]) * rg[2] * ((const float*)&gm[2])[j] + ((const float*)&bt[2])[j];
            float lo = (gq[3][j] - mg[3]) * rg[3] * ((const float*)&gm[3])[j] + ((const float*)&bt[3])[j];
            float ig = 1.0f / (1.0f + __expf(-li));
            float fg = 1.0f / (1.0f + __expf(-lf));
            float axg = fabsf(lg);
            float eg = __expf(-2.0f * axg);
            float gg = __builtin_copysignf((1.0f - eg) / (1.0f + eg), lg);
            float og = 1.0f / (1.0f + __expf(-lo));
            float rv = fg * cprev[j] + ig * gg;
            rcv[j] = rv; og4[j] = og;
            s2 += rv; q2 += rv * rv;
        }
        #pragma unroll
        for (int off = 1; off < 64; off <<= 1) { s2 += __shfl_xor(s2, off); q2 += __shfl_xor(q2, off); }
        if (lane == 0) { red2[wave] = s2; red2[8 + wave] = q2; }
        __syncthreads();   // [B] cy partials visible

        float mc, rc;
        {
            const f32x4* r4 = (const f32x4*)red2;
            f32x4 sa = r4[0], sb = r4[1], qa = r4[2], qb = r4[3];
            float s = ((sa[0] + sa[1]) + (sa[2] + sa[3])) + ((sb[0] + sb[1]) + (sb[2] + sb[3]));
            float q = ((qa[0] + qa[1]) + (qa[2] + qa[3])) + ((qb[0] + qb[1]) + (qb[2] + qb[3]));
            mc = s * invH;
            rc = rsqrtf(q * invH - mc * mc + 1e-5f);
        }

        float hvf[4], lcf[4];
        f16x4 hh;
        #pragma unroll
        for (int j = 0; j < 4; ++j) {
            float lc = (rcv[j] - mc) * rc * ((const float*)&gm4)[j] + ((const float*)&bt4)[j];
            cprev[j] = lc;
            float ax = fabsf(lc);
            float e = __expf(-2.0f * ax);
            float th = __builtin_copysignf((1.0f - e) / (1.0f + e), lc);
            float hv = og4[j] * th;
            hvf[j] = hv; lcf[j] = lc;
            hh[j] = (_Float16)hv;
        }
        *(f16x4*)&hlds[(t >> 5) * PAD_CH + ((t * 4) & 127)] = hh;

        if ((t >> 1) == b) {   // this block owns global slice [8b, 8b+8)
            float4 ho = {hvf[0], hvf[1], hvf[2], hvf[3]};
            *(float4*)&yout[(size_t)step * HD + p] = ho;
            if (step == SEQ - 1) {
                *(float4*)&hyout[p] = ho;
                float4 co = {lcf[0], lcf[1], lcf[2], lcf[3]};
                *(float4*)&cyout[p] = co;
            }
        }
        __syncthreads();   // [C] hlds ready for next GEMV
    }
}

extern "C" void kernel_launch(void* const* d_in, const int* in_sizes, int n_in,
                              void* d_out, int out_size, void* d_ws, size_t ws_size,
                              hipStream_t stream) {
    const float* x   = (const float*)d_in[0];
    const float* wih = (const float*)d_in[1];
    const float* whh = (const float*)d_in[2];
    const float* bih = (const float*)d_in[3];
    const float* bhh = (const float*)d_in[4];
    const float* gam = (const float*)d_in[5];
    const float* bet = (const float*)d_in[6];
    float* out = (float*)d_out;

    char* ws = (char*)d_ws;
    size_t off = 0;
    auto carve = [&](size_t bytes) -> void* {
        void* pp = ws + off;
        off += (bytes + 255) & ~(size_t)255;
        return pp;
    };
    float* xg      = (float*)carve(sizeof(float) * (size_t)SEQ * NG);      // 64 MB
    _Float16* whhf = (_Float16*)carve(sizeof(_Float16) * (size_t)NG * HD); // 32 MB
    float* gates   = (float*)carve(sizeof(float) * 2 * NG);
    unsigned* barctl = (unsigned*)carve(sizeof(unsigned) * 17 * 64);

    cvt_f16_kernel<<<2048, 256, 0, stream>>>(whh, whhf, NG * HD);
    dim3 ggrid(16, 64);
    gemm_xg<<<ggrid, 256, 0, stream>>>(x, wih, bih, bhh, xg);
    hipMemsetAsync(barctl, 0, sizeof(unsigned) * 17 * 64, stream);

    void* args[] = { (void*)&xg, (void*)&whhf, (void*)&gam, (void*)&bet,
                     (void*)&gates, (void*)&barctl, (void*)&out };
    hipLaunchCooperativeKernel((void*)lstm_rec, dim3(NB), dim3(NT), args, 0, stream);
}

// Round 7
// 10068.836 us; speedup vs baseline: 11.8989x; 1.3028x over previous
//
#include <hip/hip_runtime.h>

typedef float f32x2 __attribute__((ext_vector_type(2)));
typedef float f32x4 __attribute__((ext_vector_type(4)));
typedef short bf16x8 __attribute__((ext_vector_type(8)));
typedef _Float16 f16x2 __attribute__((ext_vector_type(2)));
typedef _Float16 f16x4 __attribute__((ext_vector_type(4)));
typedef _Float16 f16x8 __attribute__((ext_vector_type(8)));

#define SEQ 2048
#define HD 2048
#define NG 8192
#define KD 2048
#define NB 256
#define NT 512
#define PAD_CH 136                    // fp16 per 128-elem h-chunk incl. 8 pad (272B stride)

__device__ __forceinline__ unsigned short f32_to_bf16_rne(float f) {
    unsigned int u = __float_as_uint(f);
    u += 0x7FFFu + ((u >> 16) & 1u);
    return (unsigned short)(u >> 16);
}

__global__ void cvt_f16_kernel(const float* __restrict__ in, _Float16* __restrict__ out, int n) {
    for (int i = blockIdx.x * blockDim.x + threadIdx.x; i < n; i += gridDim.x * blockDim.x)
        out[i] = (_Float16)in[i];
}

// ---------------- GEMM: xg[s][g] = sum_k x[s][k] * w_ih[g][k] + b_ih[g] + b_hh[g] ----------------
__global__ __launch_bounds__(256) void gemm_xg(
    const float* __restrict__ A,    // x   [2048][2048]
    const float* __restrict__ B,    // w_ih[8192][2048]
    const float* __restrict__ bih, const float* __restrict__ bhh,
    float* __restrict__ C)          // xg  [2048][8192]
{
    __shared__ unsigned short As[128 * 32];
    __shared__ unsigned short Bs[128 * 32];
    const int tid = threadIdx.x;
    const int bm = blockIdx.x, bn = blockIdx.y;
    const int wave = tid >> 6, lane = tid & 63;
    const int wr = wave >> 1, wc = wave & 1;
    const int l15 = lane & 15, l4 = lane >> 4;

    f32x4 acc[4][4];
    #pragma unroll
    for (int i = 0; i < 4; ++i)
        #pragma unroll
        for (int j = 0; j < 4; ++j) {
            f32x4 z = {0.f, 0.f, 0.f, 0.f};
            acc[i][j] = z;
        }

    for (int k0 = 0; k0 < KD; k0 += 32) {
        #pragma unroll
        for (int i = 0; i < 2; ++i) {
            int idx = tid + i * 256;
            int row = idx >> 2, c8 = idx & 3;
            const float* ga = A + (size_t)(bm * 128 + row) * KD + k0 + c8 * 8;
            float4 a0 = *(const float4*)ga;
            float4 a1 = *(const float4*)(ga + 4);
            bf16x8 av;
            av[0] = (short)f32_to_bf16_rne(a0.x); av[1] = (short)f32_to_bf16_rne(a0.y);
            av[2] = (short)f32_to_bf16_rne(a0.z); av[3] = (short)f32_to_bf16_rne(a0.w);
            av[4] = (short)f32_to_bf16_rne(a1.x); av[5] = (short)f32_to_bf16_rne(a1.y);
            av[6] = (short)f32_to_bf16_rne(a1.z); av[7] = (short)f32_to_bf16_rne(a1.w);
            *(bf16x8*)&As[row * 32 + c8 * 8] = av;
            const float* gb = B + (size_t)(bn * 128 + row) * KD + k0 + c8 * 8;
            float4 b0 = *(const float4*)gb;
            float4 b1 = *(const float4*)(gb + 4);
            bf16x8 bv;
            bv[0] = (short)f32_to_bf16_rne(b0.x); bv[1] = (short)f32_to_bf16_rne(b0.y);
            bv[2] = (short)f32_to_bf16_rne(b0.z); bv[3] = (short)f32_to_bf16_rne(b0.w);
            bv[4] = (short)f32_to_bf16_rne(b1.x); bv[5] = (short)f32_to_bf16_rne(b1.y);
            bv[6] = (short)f32_to_bf16_rne(b1.z); bv[7] = (short)f32_to_bf16_rne(b1.w);
            *(bf16x8*)&Bs[row * 32 + c8 * 8] = bv;
        }
        __syncthreads();
        bf16x8 af[4], bfr[4];
        #pragma unroll
        for (int m = 0; m < 4; ++m) af[m] = *(const bf16x8*)&As[(wr * 64 + m * 16 + l15) * 32 + l4 * 8];
        #pragma unroll
        for (int n = 0; n < 4; ++n) bfr[n] = *(const bf16x8*)&Bs[(wc * 64 + n * 16 + l15) * 32 + l4 * 8];
        #pragma unroll
        for (int m = 0; m < 4; ++m)
            #pragma unroll
            for (int n = 0; n < 4; ++n)
                acc[m][n] = __builtin_amdgcn_mfma_f32_16x16x32_bf16(af[m], bfr[n], acc[m][n], 0, 0, 0);
        __syncthreads();
    }
    #pragma unroll
    for (int m = 0; m < 4; ++m) {
        #pragma unroll
        for (int n = 0; n < 4; ++n) {
            int col = bn * 128 + wc * 64 + n * 16 + l15;
            float bias = bih[col] + bhh[col];
            int row0 = bm * 128 + wr * 64 + m * 16 + l4 * 4;
            #pragma unroll
            for (int r = 0; r < 4; ++r)
                C[(size_t)(row0 + r) * NG + col] = acc[m][n][r] + bias;
        }
    }
}

// ---- LLC-coherent primitives (agent scope; no cache-wide fences anywhere) ----
__device__ __forceinline__ void st_llc16(float* p, f32x4 v) {
    asm volatile("global_store_dwordx4 %0, %1, off sc0 sc1" :: "v"(p), "v"(v) : "memory");
}
__device__ __forceinline__ void st_llc8(float* p, f32x2 v) {
    asm volatile("global_store_dwordx2 %0, %1, off sc0 sc1" :: "v"(p), "v"(v) : "memory");
}
// issue 4 coherent 16B loads, NO wait (overlap with independent work)
__device__ __forceinline__ void ld_llc_issue4(const float* p0, const float* p1,
                                              const float* p2, const float* p3,
                                              f32x4& a, f32x4& b, f32x4& c, f32x4& d) {
    asm volatile(
        "global_load_dwordx4 %0, %4, off sc0 sc1\n\t"
        "global_load_dwordx4 %1, %5, off sc0 sc1\n\t"
        "global_load_dwordx4 %2, %6, off sc0 sc1\n\t"
        "global_load_dwordx4 %3, %7, off sc0 sc1"
        : "=&v"(a), "=&v"(b), "=&v"(c), "=&v"(d)
        : "v"(p0), "v"(p1), "v"(p2), "v"(p3)
        : "memory");
}
__device__ __forceinline__ void wait_vm0_4(f32x4& a, f32x4& b, f32x4& c, f32x4& d) {
    asm volatile("s_waitcnt vmcnt(0)" : "+v"(a), "+v"(b), "+v"(c), "+v"(d) :: "memory");
    __builtin_amdgcn_sched_barrier(0);
}
// 4 coherent 16B loads + wait; offset immediate BEFORE cache flags (gfx950 asm order)
__device__ __forceinline__ void ld_llc_4x4_wait(const float* p, f32x4& a, f32x4& b, f32x4& c, f32x4& d) {
    asm volatile(
        "global_load_dwordx4 %0, %4, off sc0 sc1\n\t"
        "global_load_dwordx4 %1, %4, off offset:16 sc0 sc1\n\t"
        "global_load_dwordx4 %2, %4, off offset:32 sc0 sc1\n\t"
        "global_load_dwordx4 %3, %4, off offset:48 sc0 sc1\n\t"
        "s_waitcnt vmcnt(0)"
        : "=&v"(a), "=&v"(b), "=&v"(c), "=&v"(d)
        : "v"(p)
        : "memory");
    __builtin_amdgcn_sched_barrier(0);
}
// untracked plain load (normal caching) for xg prefetch
__device__ __forceinline__ void ld_gl16(const float* p, f32x4& a) {
    asm volatile("global_load_dwordx4 %0, %1, off" : "=&v"(a) : "v"(p) : "memory");
}

__device__ __forceinline__ float rcpf(float x) { return __builtin_amdgcn_rcpf(x); }
__device__ __forceinline__ float rsqf(float x) { return __builtin_amdgcn_rsqf(x); }
__device__ __forceinline__ float sigf(float x) { return rcpf(1.0f + __expf(-x)); }
__device__ __forceinline__ float tanhfast(float x) {
    float ax = fabsf(x);
    float e = __expf(-2.0f * ax);
    return __builtin_copysignf((1.0f - e) * rcpf(1.0f + e), x);
}

// barctl layout (unsigned, 64-word = 256B spacing):
//   [g*64] g=0..7 group counters (32 blocks) | [8*64] root | [(9+g)*64] relays
#define ROOT_OFF (8 * 64)
#define RELAY_OFF (9 * 64)

// ---------------- Persistent recurrence: 1 tree-barrier per step ----------------
__global__ __launch_bounds__(512, 2) void lstm_rec(
    const float* __restrict__ xg,          // [SEQ][NG]
    const _Float16* __restrict__ Whh,      // [NG][HD] fp16
    const float* __restrict__ gamma,       // [5][HD]
    const float* __restrict__ beta,        // [5][HD]
    float* __restrict__ gates,             // [2][NG] double-buffered
    float* __restrict__ partials,          // [2][2048]{s,q} per (block,wave), dbuffered
    unsigned* __restrict__ barctl,
    float* __restrict__ yout)              // y[SEQ][HD], hy[HD], cy[HD]
{
    __shared__ _Float16 hlds[16 * PAD_CH];
    __shared__ __align__(16) float red2[16];   // cy partials [s: w | q: 8+w]
    __shared__ __align__(16) float statsmem[8]; // 4 gates x {m, r}

    const int b = blockIdx.x;
    const int t = threadIdx.x;
    const int wave = t >> 6, lane = t & 63;
    const int p = t * 4;                   // this thread's 4 H-positions

    unsigned* grpcnt = barctl + (b >> 5) * 64;
    unsigned* rootcnt = barctl + ROOT_OFF;
    unsigned* relay = barctl + RELAY_OFF + (b >> 5) * 64;

    const int row = t >> 4, sub = t & 15;  // GEMV: row 0..31, 128-col chunk
    const int grow = b * 32 + row;

    // ---- W strip -> 64 VGPRs (one-time) ----
    f16x8 wreg[16];
    {
        const _Float16* wsrc = Whh + (size_t)grow * HD + sub * 128;
        #pragma unroll
        for (int i = 0; i < 16; ++i) wreg[i] = *(const f16x8*)(wsrc + i * 8);
    }
    for (int k = t; k < 16 * PAD_CH; k += NT) hlds[k] = (_Float16)0.0f;

    float4 gm[4], bt[4];
    #pragma unroll
    for (int g = 0; g < 4; ++g) {
        gm[g] = *(const float4*)&gamma[g * HD + p];
        bt[g] = *(const float4*)&beta[g * HD + p];
    }
    float4 gm4 = *(const float4*)&gamma[4 * HD + p];
    float4 bt4 = *(const float4*)&beta[4 * HD + p];

    float* hyout = yout + (size_t)SEQ * HD;
    float* cyout = hyout + HD;
    const float invH = 1.0f / 2048.0f;

    float cprev[4] = {0.f, 0.f, 0.f, 0.f};

    // lane0 of wave w holds xg f32x4 for rows b*32 + 4w .. +3
    f32x4 xg4 = {0.f, 0.f, 0.f, 0.f};
    if (lane == 0) xg4 = *(const f32x4*)(xg + b * 32 + wave * 4);

    const _Float16* hch = hlds + sub * PAD_CH;
    __syncthreads();

    for (int step = 0; step < SEQ; ++step) {
        float* gb = gates + (size_t)(step & 1) * NG;
        float* pb = partials + (size_t)(step & 1) * (NB * 8 * 2);
        const unsigned gen = (unsigned)(step + 1);

        // ---------- GEMV from registers; h via LDS broadcast ----------
        float accv[4] = {0.f, 0.f, 0.f, 0.f};
        #pragma unroll
        for (int i = 0; i < 16; ++i) {
            f16x8 hv = *(const f16x8*)(hch + i * 8);
            const f16x2* w2 = (const f16x2*)&wreg[i];
            const f16x2* h2 = (const f16x2*)&hv;
            float x = accv[i & 3];
            x = __builtin_amdgcn_fdot2(w2[0], h2[0], x, false);
            x = __builtin_amdgcn_fdot2(w2[1], h2[1], x, false);
            x = __builtin_amdgcn_fdot2(w2[2], h2[2], x, false);
            x = __builtin_amdgcn_fdot2(w2[3], h2[3], x, false);
            accv[i & 3] = x;
        }
        float r = (accv[0] + accv[1]) + (accv[2] + accv[3]);
        #pragma unroll
        for (int off = 1; off < 16; off <<= 1) r += __shfl_xor(r, off);
        float r1 = __shfl(r, 16), r2 = __shfl(r, 32), r3 = __shfl(r, 48);
        if (lane == 0) {
            f32x4 gv4 = {r + xg4[0], r1 + xg4[1], r2 + xg4[2], r3 + xg4[3]};
            st_llc16(&gb[b * 32 + wave * 4], gv4);
            // pre-barrier partial stats of this wave's 4 gate values
            float s4 = (gv4[0] + gv4[1]) + (gv4[2] + gv4[3]);
            float q4 = (gv4[0] * gv4[0] + gv4[1] * gv4[1]) + (gv4[2] * gv4[2] + gv4[3] * gv4[3]);
            f32x2 pq = {s4, q4};
            st_llc8(&pb[(b * 8 + wave) * 2], pq);
        }

        __syncthreads();   // drains all waves' stores (vmcnt 0) before arrival

        // ---------- tree arrival (t0 only) ----------
        if (t == 0) {
            asm volatile("" ::: "memory");
            unsigned o1 = __hip_atomic_fetch_add(grpcnt, 1u, __ATOMIC_RELAXED, __HIP_MEMORY_SCOPE_AGENT);
            if (o1 == gen * 32u - 1u) {
                unsigned o2 = __hip_atomic_fetch_add(rootcnt, 1u, __ATOMIC_RELAXED, __HIP_MEMORY_SCOPE_AGENT);
                if (o2 == gen * 8u - 1u) {
                    #pragma unroll
                    for (int g = 0; g < 8; ++g)
                        __hip_atomic_store(barctl + RELAY_OFF + g * 64, gen,
                                           __ATOMIC_RELAXED, __HIP_MEMORY_SCOPE_AGENT);
                }
            }
        }
        // ---------- wave self-release ----------
        for (;;) {
            unsigned rv = __hip_atomic_load(relay, __ATOMIC_RELAXED, __HIP_MEMORY_SCOPE_AGENT);
            if (rv >= gen) break;
            __builtin_amdgcn_s_sleep(1);
        }
        asm volatile("" ::: "memory");

        // ---------- post-phase ----------
        // issue gate loads immediately (wait deferred past stats)
        f32x4 gq[4];
        ld_llc_issue4(&gb[0 * HD + p], &gb[1 * HD + p], &gb[2 * HD + p], &gb[3 * HD + p],
                      gq[0], gq[1], gq[2], gq[3]);
        // prefetch next step's xg (untracked; drained by wait_vm0_4 below)
        if (lane == 0 && step + 1 < SEQ)
            ld_gl16(xg + (size_t)(step + 1) * NG + b * 32 + wave * 4, xg4);

        // waves 0..3: reduce 512 block-partials of gate `wave` (in parallel with gq flight)
        if (wave < 4) {
            f32x4 pa, pbv, pc, pd;
            ld_llc_4x4_wait(&pb[wave * 1024 + lane * 16], pa, pbv, pc, pd);
            float s = ((pa[0] + pa[2]) + (pbv[0] + pbv[2])) + ((pc[0] + pc[2]) + (pd[0] + pd[2]));
            float q = ((pa[1] + pa[3]) + (pbv[1] + pbv[3])) + ((pc[1] + pc[3]) + (pd[1] + pd[3]));
            #pragma unroll
            for (int off = 1; off < 64; off <<= 1) { s += __shfl_xor(s, off); q += __shfl_xor(q, off); }
            if (lane == 0) {
                float m = s * invH;
                statsmem[wave * 2] = m;
                statsmem[wave * 2 + 1] = rsqf(q * invH - m * m + 1e-5f);
            }
        }
        __syncthreads();   // [A] stats visible

        wait_vm0_4(gq[0], gq[1], gq[2], gq[3]);
        float mg[4], rg[4];
        {
            const f32x4* sm = (const f32x4*)statsmem;
            f32x4 s0 = sm[0], s1 = sm[1];
            mg[0] = s0[0]; rg[0] = s0[1]; mg[1] = s0[2]; rg[1] = s0[3];
            mg[2] = s1[0]; rg[2] = s1[1]; mg[3] = s1[2]; rg[3] = s1[3];
        }

        float rcv[4], og4[4];
        float s2 = 0.f, q2 = 0.f;
        #pragma unroll
        for (int j = 0; j < 4; ++j) {
            float li = (gq[0][j] - mg[0]) * rg[0] * ((const float*)&gm[0])[j] + ((const float*)&bt[0])[j];
            float lf = (gq[1][j] - mg[1]) * rg[1] * ((const float*)&gm[1])[j] + ((const float*)&bt[1])[j];
            float lg = (gq[2][j] - mg[2]) * rg[2] * ((const float*)&gm[2])[j] + ((const float*)&bt[2])[j];
            float lo = (gq[3][j] - mg[3]) * rg[3] * ((const float*)&gm[3])[j] + ((const float*)&bt[3])[j];
            float ig = sigf(li);
            float fg = sigf(lf);
            float gg = tanhfast(lg);
            float og = sigf(lo);
            float rv = fg * cprev[j] + ig * gg;
            rcv[j] = rv; og4[j] = og;
            s2 += rv; q2 += rv * rv;
        }
        #pragma unroll
        for (int off = 1; off < 64; off <<= 1) { s2 += __shfl_xor(s2, off); q2 += __shfl_xor(q2, off); }
        if (lane == 0) { red2[wave] = s2; red2[8 + wave] = q2; }
        __syncthreads();   // [B] cy partials visible

        float mc, rc;
        {
            const f32x4* r4 = (const f32x4*)red2;
            f32x4 sa = r4[0], sb = r4[1], qa = r4[2], qb = r4[3];
            float s = ((sa[0] + sa[1]) + (sa[2] + sa[3])) + ((sb[0] + sb[1]) + (sb[2] + sb[3]));
            float q = ((qa[0] + qa[1]) + (qa[2] + qa[3])) + ((qb[0] + qb[1]) + (qb[2] + qb[3]));
            mc = s * invH;
            rc = rsqf(q * invH - mc * mc + 1e-5f);
        }

        float hvf[4], lcf[4];
        f16x4 hh;
        #pragma unroll
        for (int j = 0; j < 4; ++j) {
            float lc = (rcv[j] - mc) * rc * ((const float*)&gm4)[j] + ((const float*)&bt4)[j];
            cprev[j] = lc;
            float th = tanhfast(lc);
            float hv = og4[j] * th;
            hvf[j] = hv; lcf[j] = lc;
            hh[j] = (_Float16)hv;
        }
        *(f16x4*)&hlds[(t >> 5) * PAD_CH + (p & 127)] = hh;

        if ((t >> 1) == b) {   // this block owns global slice [8b, 8b+8)
            float4 ho = {hvf[0], hvf[1], hvf[2], hvf[3]};
            *(float4*)&yout[(size_t)step * HD + p] = ho;
            if (step == SEQ - 1) {
                *(float4*)&hyout[p] = ho;
                float4 co = {lcf[0], lcf[1], lcf[2], lcf[3]};
                *(float4*)&cyout[p] = co;
            }
        }
        __syncthreads();   // [C] hlds ready for next GEMV
    }
}

extern "C" void kernel_launch(void* const* d_in, const int* in_sizes, int n_in,
                              void* d_out, int out_size, void* d_ws, size_t ws_size,
                              hipStream_t stream) {
    const float* x   = (const float*)d_in[0];
    const float* wih = (const float*)d_in[1];
    const float* whh = (const float*)d_in[2];
    const float* bih = (const float*)d_in[3];
    const float* bhh = (const float*)d_in[4];
    const float* gam = (const float*)d_in[5];
    const float* bet = (const float*)d_in[6];
    float* out = (float*)d_out;

    char* ws = (char*)d_ws;
    size_t off = 0;
    auto carve = [&](size_t bytes) -> void* {
        void* pp = ws + off;
        off += (bytes + 255) & ~(size_t)255;
        return pp;
    };
    float* xg      = (float*)carve(sizeof(float) * (size_t)SEQ * NG);      // 64 MB
    _Float16* whhf = (_Float16*)carve(sizeof(_Float16) * (size_t)NG * HD); // 32 MB
    float* gates   = (float*)carve(sizeof(float) * 2 * NG);
    float* parts   = (float*)carve(sizeof(float) * 2 * NB * 8 * 2);
    unsigned* barctl = (unsigned*)carve(sizeof(unsigned) * 17 * 64);

    cvt_f16_kernel<<<2048, 256, 0, stream>>>(whh, whhf, NG * HD);
    dim3 ggrid(16, 64);
    gemm_xg<<<ggrid, 256, 0, stream>>>(x, wih, bih, bhh, xg);
    hipMemsetAsync(barctl, 0, sizeof(unsigned) * 17 * 64, stream);

    void* args[] = { (void*)&xg, (void*)&whhf, (void*)&gam, (void*)&bet,
                     (void*)&gates, (void*)&parts, (void*)&barctl, (void*)&out };
    hipLaunchCooperativeKernel((void*)lstm_rec, dim3(NB), dim3(NT), args, 0, stream);
}